// Round 1
// baseline (2629.142 us; speedup 1.0000x reference)
//
#include <hip/hip_runtime.h>
#include <cstddef>

namespace {

constexpr int Gn  = 64;
constexpr int Pn  = 512;
constexpr int EPGn= 4096;
constexpr int Nn  = Gn * Pn;    // 32768 nodes
constexpr int En  = Gn * EPGn;  // 262144 edges
constexpr int H   = 128;

constexpr int BM = 64, BK = 32, BN = 128;
constexpr int LDA = BK + 4;   // 36 floats, 144B rows (16B aligned)
constexpr int LDH = BN + 4;   // 132 floats, 528B rows (16B aligned)

__device__ __forceinline__ float4 ld4(const float* p) { return *reinterpret_cast<const float4*>(p); }
__device__ __forceinline__ void st4(float* p, const float4 v) { *reinterpret_cast<float4*>(p) = v; }

// ---------------------------------------------------------------------------
// Generic fused 2-layer MLP + LayerNorm over gathered/concatenated segments.
// Each segment is H=128 wide. out = LN(relu(A @ W1 + b1) @ W2 + b2) * gam + bet
// A row = concat over segments of  p[seg][ idx?idx[row]:row ][:] * (sc?sc[srow]:1)
// Block: 256 threads, BM=64 rows, full BN=128 output width.
// Thread micro-tile: 4 rows x 8 cols. rg=tid>>4 (16), cg=tid&15 (16).
// ---------------------------------------------------------------------------
template<int NSEG>
__global__ __launch_bounds__(256, 2)
void fused_mlp_ln(const float* __restrict__ p0, const int* __restrict__ i0, const float* __restrict__ s0,
                  const float* __restrict__ p1, const int* __restrict__ i1, const float* __restrict__ s1,
                  const float* __restrict__ p2, const int* __restrict__ i2, const float* __restrict__ s2,
                  const float* __restrict__ p3, const int* __restrict__ i3, const float* __restrict__ s3,
                  const float* __restrict__ W1, const float* __restrict__ b1,
                  const float* __restrict__ W2, const float* __restrict__ b2,
                  const float* __restrict__ gam, const float* __restrict__ bet,
                  float* __restrict__ outp)
{
    __shared__ float sA[BM * LDA];
    __shared__ float sW[BK * BN];
    __shared__ float sH[BM * LDH];

    const int tid = threadIdx.x;
    const int rg = tid >> 4, cg = tid & 15;
    const int m0 = rg * 4, n0 = cg * 8;
    const int row0 = blockIdx.x * BM;

    const int lr = tid >> 2;           // A-stage: row 0..63
    const int lc = (tid & 3) * 8;      // A-stage: col 0/8/16/24
    const int wr = tid >> 3;           // W-stage: row 0..31
    const int wc = (tid & 7) * 16;     // W-stage: col 0..112

    float acc[4][8];
#pragma unroll
    for (int i = 0; i < 4; ++i)
#pragma unroll
        for (int j = 0; j < 8; ++j) acc[i][j] = 0.f;

    // ---------------- phase 1: hidden = A @ W1 ----------------
#pragma unroll 1
    for (int kc = 0; kc < NSEG * 4; ++kc) {
        const int seg  = kc >> 2;
        const int koff = (kc & 3) * 32;
        const float* p; const int* ix; const float* sc;
        if (seg == 0)      { p = p0; ix = i0; sc = s0; }
        else if (seg == 1) { p = p1; ix = i1; sc = s1; }
        else if (seg == 2) { p = p2; ix = i2; sc = s2; }
        else               { p = p3; ix = i3; sc = s3; }

        const int grow = row0 + lr;
        const int srow = ix ? ix[grow] : grow;
        const float* srcp = p + (size_t)srow * H + koff + lc;
        float4 a0 = ld4(srcp);
        float4 a1 = ld4(srcp + 4);
        if (sc) {
            const float s = sc[srow];
            a0.x *= s; a0.y *= s; a0.z *= s; a0.w *= s;
            a1.x *= s; a1.y *= s; a1.z *= s; a1.w *= s;
        }
        st4(&sA[lr * LDA + lc],     a0);
        st4(&sA[lr * LDA + lc + 4], a1);

        const float* wsrc = W1 + (size_t)(seg * H + koff) * BN + wr * BN + wc;
        st4(&sW[wr * BN + wc],      ld4(wsrc));
        st4(&sW[wr * BN + wc + 4],  ld4(wsrc + 4));
        st4(&sW[wr * BN + wc + 8],  ld4(wsrc + 8));
        st4(&sW[wr * BN + wc + 12], ld4(wsrc + 12));
        __syncthreads();

#pragma unroll
        for (int kk = 0; kk < BK; ++kk) {
            float a[4];
#pragma unroll
            for (int i = 0; i < 4; ++i) a[i] = sA[(m0 + i) * LDA + kk];
            const float4 wA = ld4(&sW[kk * BN + n0]);
            const float4 wB = ld4(&sW[kk * BN + n0 + 4]);
            const float w[8] = {wA.x, wA.y, wA.z, wA.w, wB.x, wB.y, wB.z, wB.w};
#pragma unroll
            for (int i = 0; i < 4; ++i)
#pragma unroll
                for (int j = 0; j < 8; ++j)
                    acc[i][j] = fmaf(a[i], w[j], acc[i][j]);
        }
        __syncthreads();
    }

    // bias + relu -> sH; reset acc for phase 2
    {
        const float4 bA = ld4(&b1[n0]);
        const float4 bB = ld4(&b1[n0 + 4]);
        const float bb[8] = {bA.x, bA.y, bA.z, bA.w, bB.x, bB.y, bB.z, bB.w};
#pragma unroll
        for (int i = 0; i < 4; ++i) {
            float h[8];
#pragma unroll
            for (int j = 0; j < 8; ++j) {
                float v = acc[i][j] + bb[j];
                h[j] = v > 0.f ? v : 0.f;
                acc[i][j] = 0.f;
            }
            st4(&sH[(m0 + i) * LDH + n0],     make_float4(h[0], h[1], h[2], h[3]));
            st4(&sH[(m0 + i) * LDH + n0 + 4], make_float4(h[4], h[5], h[6], h[7]));
        }
    }

    // ---------------- phase 2: out = relu(hidden) @ W2 ----------------
#pragma unroll 1
    for (int kc = 0; kc < 4; ++kc) {
        const int koff = kc * 32;
        const float* wsrc = W2 + (size_t)koff * BN + wr * BN + wc;
        st4(&sW[wr * BN + wc],      ld4(wsrc));
        st4(&sW[wr * BN + wc + 4],  ld4(wsrc + 4));
        st4(&sW[wr * BN + wc + 8],  ld4(wsrc + 8));
        st4(&sW[wr * BN + wc + 12], ld4(wsrc + 12));
        __syncthreads();   // also fences the sH writes above on first iter

#pragma unroll
        for (int kk = 0; kk < BK; ++kk) {
            float a[4];
#pragma unroll
            for (int i = 0; i < 4; ++i) a[i] = sH[(m0 + i) * LDH + koff + kk];
            const float4 wA = ld4(&sW[kk * BN + n0]);
            const float4 wB = ld4(&sW[kk * BN + n0 + 4]);
            const float w[8] = {wA.x, wA.y, wA.z, wA.w, wB.x, wB.y, wB.z, wB.w};
#pragma unroll
            for (int i = 0; i < 4; ++i)
#pragma unroll
                for (int j = 0; j < 8; ++j)
                    acc[i][j] = fmaf(a[i], w[j], acc[i][j]);
        }
        __syncthreads();
    }

    // ---------------- bias + LayerNorm + affine, store ----------------
    {
        const float4 bA = ld4(&b2[n0]),  bB = ld4(&b2[n0 + 4]);
        const float4 gA = ld4(&gam[n0]), gB = ld4(&gam[n0 + 4]);
        const float4 tA = ld4(&bet[n0]), tB = ld4(&bet[n0 + 4]);
        const float bb[8] = {bA.x, bA.y, bA.z, bA.w, bB.x, bB.y, bB.z, bB.w};
        const float gg[8] = {gA.x, gA.y, gA.z, gA.w, gB.x, gB.y, gB.z, gB.w};
        const float tt[8] = {tA.x, tA.y, tA.z, tA.w, tB.x, tB.y, tB.z, tB.w};
#pragma unroll
        for (int i = 0; i < 4; ++i) {
            float v[8];
            float s = 0.f;
#pragma unroll
            for (int j = 0; j < 8; ++j) { v[j] = acc[i][j] + bb[j]; s += v[j]; }
            // row spread over the 16 cg-lanes of this rg (lanes are contiguous)
            s += __shfl_xor(s, 1, 16); s += __shfl_xor(s, 2, 16);
            s += __shfl_xor(s, 4, 16); s += __shfl_xor(s, 8, 16);
            const float mean = s * (1.f / 128.f);
            float q = 0.f;
#pragma unroll
            for (int j = 0; j < 8; ++j) { const float d = v[j] - mean; q += d * d; }
            q += __shfl_xor(q, 1, 16); q += __shfl_xor(q, 2, 16);
            q += __shfl_xor(q, 4, 16); q += __shfl_xor(q, 8, 16);
            const float rstd = rsqrtf(q * (1.f / 128.f) + 1e-5f);
            float o[8];
#pragma unroll
            for (int j = 0; j < 8; ++j) o[j] = (v[j] - mean) * rstd * gg[j] + tt[j];
            float* op = outp + (size_t)(row0 + m0 + i) * H + n0;
            st4(op,     make_float4(o[0], o[1], o[2], o[3]));
            st4(op + 4, make_float4(o[4], o[5], o[6], o[7]));
        }
    }
}

// ---------------------------------------------------------------------------
// Input projection: out = relu(in[rows,K] @ W[K,128] + b), K in {64,32}
// ---------------------------------------------------------------------------
template<int K>
__global__ __launch_bounds__(256, 2)
void proj_relu(const float* __restrict__ in, const float* __restrict__ W,
               const float* __restrict__ b, float* __restrict__ out)
{
    constexpr int LDAP = K + 4;
    __shared__ float sA[BM * LDAP];
    __shared__ float sWp[K * BN];

    const int tid = threadIdx.x;
    const int rg = tid >> 4, cg = tid & 15;
    const int m0 = rg * 4, n0 = cg * 8;
    const int row0 = blockIdx.x * BM;

    if constexpr (K == 64) {
        const int lr = tid >> 2, lc = (tid & 3) * 16;
        const float* srcp = in + (size_t)(row0 + lr) * K + lc;
#pragma unroll
        for (int q = 0; q < 16; q += 4) st4(&sA[lr * LDAP + lc + q], ld4(srcp + q));
        const int wrk = tid >> 2, wck = (tid & 3) * 32;
        const float* wsp = W + (size_t)wrk * BN + wck;
#pragma unroll
        for (int q = 0; q < 32; q += 4) st4(&sWp[wrk * BN + wck + q], ld4(wsp + q));
    } else {
        const int lr = tid >> 2, lc = (tid & 3) * 8;
        const float* srcp = in + (size_t)(row0 + lr) * K + lc;
        st4(&sA[lr * LDAP + lc],     ld4(srcp));
        st4(&sA[lr * LDAP + lc + 4], ld4(srcp + 4));
        const int wrk = tid >> 3, wck = (tid & 7) * 16;
        const float* wsp = W + (size_t)wrk * BN + wck;
#pragma unroll
        for (int q = 0; q < 16; q += 4) st4(&sWp[wrk * BN + wck + q], ld4(wsp + q));
    }
    __syncthreads();

    float acc[4][8];
#pragma unroll
    for (int i = 0; i < 4; ++i)
#pragma unroll
        for (int j = 0; j < 8; ++j) acc[i][j] = 0.f;

#pragma unroll 8
    for (int k = 0; k < K; ++k) {
        float a[4];
#pragma unroll
        for (int i = 0; i < 4; ++i) a[i] = sA[(m0 + i) * LDAP + k];
        const float4 wA = ld4(&sWp[k * BN + n0]);
        const float4 wB = ld4(&sWp[k * BN + n0 + 4]);
        const float w[8] = {wA.x, wA.y, wA.z, wA.w, wB.x, wB.y, wB.z, wB.w};
#pragma unroll
        for (int i = 0; i < 4; ++i)
#pragma unroll
            for (int j = 0; j < 8; ++j)
                acc[i][j] = fmaf(a[i], w[j], acc[i][j]);
    }

    const float4 bA = ld4(&b[n0]), bB = ld4(&b[n0 + 4]);
    const float bb[8] = {bA.x, bA.y, bA.z, bA.w, bB.x, bB.y, bB.z, bB.w};
#pragma unroll
    for (int i = 0; i < 4; ++i) {
        float o[8];
#pragma unroll
        for (int j = 0; j < 8; ++j) {
            const float v = acc[i][j] + bb[j];
            o[j] = v > 0.f ? v : 0.f;
        }
        float* op = out + (size_t)(row0 + m0 + i) * H + n0;
        st4(op,     make_float4(o[0], o[1], o[2], o[3]));
        st4(op + 4, make_float4(o[4], o[5], o[6], o[7]));
    }
}

// ---------------------------------------------------------------------------
// Head: out[row] = relu(in[row,:] @ W1 + b1) . w2 + b2[0]
// ---------------------------------------------------------------------------
__global__ __launch_bounds__(256, 2)
void head_mlp(const float* __restrict__ in, const float* __restrict__ W1,
              const float* __restrict__ b1, const float* __restrict__ w2,
              const float* __restrict__ b2, float* __restrict__ outp)
{
    __shared__ float sA[BM * LDA];
    __shared__ float sW[BK * BN];

    const int tid = threadIdx.x;
    const int rg = tid >> 4, cg = tid & 15;
    const int m0 = rg * 4, n0 = cg * 8;
    const int row0 = blockIdx.x * BM;
    const int lr = tid >> 2, lc = (tid & 3) * 8;
    const int wr = tid >> 3, wc = (tid & 7) * 16;

    float acc[4][8];
#pragma unroll
    for (int i = 0; i < 4; ++i)
#pragma unroll
        for (int j = 0; j < 8; ++j) acc[i][j] = 0.f;

#pragma unroll 1
    for (int kc = 0; kc < 4; ++kc) {
        const int koff = kc * 32;
        const float* srcp = in + (size_t)(row0 + lr) * H + koff + lc;
        st4(&sA[lr * LDA + lc],     ld4(srcp));
        st4(&sA[lr * LDA + lc + 4], ld4(srcp + 4));
        const float* wsrc = W1 + (size_t)koff * BN + wr * BN + wc;
        st4(&sW[wr * BN + wc],      ld4(wsrc));
        st4(&sW[wr * BN + wc + 4],  ld4(wsrc + 4));
        st4(&sW[wr * BN + wc + 8],  ld4(wsrc + 8));
        st4(&sW[wr * BN + wc + 12], ld4(wsrc + 12));
        __syncthreads();
#pragma unroll
        for (int kk = 0; kk < BK; ++kk) {
            float a[4];
#pragma unroll
            for (int i = 0; i < 4; ++i) a[i] = sA[(m0 + i) * LDA + kk];
            const float4 wA = ld4(&sW[kk * BN + n0]);
            const float4 wB = ld4(&sW[kk * BN + n0 + 4]);
            const float w[8] = {wA.x, wA.y, wA.z, wA.w, wB.x, wB.y, wB.z, wB.w};
#pragma unroll
            for (int i = 0; i < 4; ++i)
#pragma unroll
                for (int j = 0; j < 8; ++j)
                    acc[i][j] = fmaf(a[i], w[j], acc[i][j]);
        }
        __syncthreads();
    }

    const float4 bA = ld4(&b1[n0]),  bB = ld4(&b1[n0 + 4]);
    const float4 vA = ld4(&w2[n0]),  vB = ld4(&w2[n0 + 4]);
    const float bb[8] = {bA.x, bA.y, bA.z, bA.w, bB.x, bB.y, bB.z, bB.w};
    const float vv[8] = {vA.x, vA.y, vA.z, vA.w, vB.x, vB.y, vB.z, vB.w};
#pragma unroll
    for (int i = 0; i < 4; ++i) {
        float p = 0.f;
#pragma unroll
        for (int j = 0; j < 8; ++j) {
            float h = acc[i][j] + bb[j];
            h = h > 0.f ? h : 0.f;
            p = fmaf(h, vv[j], p);
        }
        p += __shfl_xor(p, 1, 16); p += __shfl_xor(p, 2, 16);
        p += __shfl_xor(p, 4, 16); p += __shfl_xor(p, 8, 16);
        if (cg == 0) outp[row0 + m0 + i] = p + b2[0];
    }
}

// ---------------------------------------------------------------------------
// small utility kernels
// ---------------------------------------------------------------------------
__global__ void init_u_k(float* __restrict__ u, const float* __restrict__ u0)
{
    const int idx = blockIdx.x * 256 + threadIdx.x;   // < 64*128
    u[idx] = u0[idx & (H - 1)];
}

__global__ void make_ebatch_k(const int* __restrict__ src, const int* __restrict__ batch,
                              int* __restrict__ eb)
{
    const int i = blockIdx.x * 256 + threadIdx.x;     // < E
    eb[i] = batch[src[i]];
}

__global__ void count_deg_k(const int* __restrict__ dst, float* __restrict__ deg)
{
    const int i = blockIdx.x * 256 + threadIdx.x;     // < E
    atomicAdd(&deg[dst[i]], 1.0f);
}

__global__ void inv_deg_k(float* __restrict__ deg)
{
    const int i = blockIdx.x * 256 + threadIdx.x;     // < N
    deg[i] = 1.0f / fmaxf(deg[i], 1.0f);
}

__global__ void scatter_add_k(const float* __restrict__ e, const int* __restrict__ dst,
                              float* __restrict__ agg)
{
    const int idx = blockIdx.x * 256 + threadIdx.x;   // < E*32
    const int edge = idx >> 5;
    const int q = (idx & 31) * 4;
    const float4 v = ld4(&e[(size_t)edge * H + q]);
    float* a = &agg[(size_t)dst[edge] * H + q];
    atomicAdd(a + 0, v.x); atomicAdd(a + 1, v.y);
    atomicAdd(a + 2, v.z); atomicAdd(a + 3, v.w);
}

// mean-pool rows of `in` per graph; grid = Gn*splits blocks
__global__ void pool_mean_k(const float* __restrict__ in, float* __restrict__ out,
                            int rpg, int splits, float scale)
{
    const int g  = blockIdx.x / splits;
    const int sp = blockIdx.x % splits;
    const int rpb = rpg / splits;
    const int tid = threadIdx.x;
    const int col = tid & (H - 1);
    const int half = tid >> 7;
    const size_t base = ((size_t)g * rpg + (size_t)sp * rpb) * H;
    float s = 0.f;
    const int r0 = half * (rpb / 2), r1 = r0 + rpb / 2;
    for (int r = r0; r < r1; ++r) s += in[base + (size_t)r * H + col];
    __shared__ float red[256];
    red[tid] = s;
    __syncthreads();
    if (half == 0) atomicAdd(&out[g * H + col], (red[col] + red[128 + col]) * scale);
}

// per-graph: actions (argmax), logprob of action, entropy. 512 logits/graph.
__global__ void softmax_head_k(const float* __restrict__ logits, float* __restrict__ outp)
{
    const int g = blockIdx.x;
    const int tid = threadIdx.x;
    const float* lg = logits + (size_t)g * Pn;
    const float v0 = lg[tid], v1 = lg[tid + 256];
    float bv; int bi;
    if (v1 > v0) { bv = v1; bi = tid + 256; } else { bv = v0; bi = tid; }

    __shared__ float sv[256];
    __shared__ int   si[256];
    sv[tid] = bv; si[tid] = bi;
    __syncthreads();
    for (int s = 128; s > 0; s >>= 1) {
        if (tid < s) {
            const float ov = sv[tid + s]; const int oi = si[tid + s];
            if (ov > sv[tid] || (ov == sv[tid] && oi < si[tid])) { sv[tid] = ov; si[tid] = oi; }
        }
        __syncthreads();
    }
    const float mx = sv[0];
    const int ai = si[0];
    __syncthreads();

    const float d0 = v0 - mx, d1 = v1 - mx;
    const float e0 = __expf(d0) , e1 = __expf(d1);
    __shared__ float ss[256];
    __shared__ float st[256];
    ss[tid] = e0 + e1;
    st[tid] = e0 * d0 + e1 * d1;
    __syncthreads();
    for (int s = 128; s > 0; s >>= 1) {
        if (tid < s) { ss[tid] += ss[tid + s]; st[tid] += st[tid + s]; }
        __syncthreads();
    }
    if (tid == 0) {
        const float S = ss[0];
        const float logS = logf(S);
        outp[g]            = (float)ai;          // actions
        outp[Gn + g]       = -logS;              // logprobs (logit[amax]-mx = 0)
        outp[2 * Gn + g]   = logS - st[0] / S;   // entropy
    }
}

} // namespace

extern "C" void kernel_launch(void* const* d_in, const int* in_sizes, int n_in,
                              void* d_out, int out_size, void* d_ws, size_t ws_size,
                              hipStream_t stream)
{
    (void)in_sizes; (void)n_in; (void)out_size; (void)ws_size;

    const float* x     = (const float*)d_in[0];
    const float* ea    = (const float*)d_in[1];
    const int*   ei    = (const int*)d_in[2];
    const int*   batch = (const int*)d_in[3];
    // d_in[4] = mask (all true), d_in[5] = num_graphs (=64): unused
    const float* Wn  = (const float*)d_in[6];
    const float* bn_ = (const float*)d_in[7];
    const float* We  = (const float*)d_in[8];
    const float* be_ = (const float*)d_in[9];
    const float* u0  = (const float*)d_in[10];
    const float* eW1 = (const float*)d_in[11];
    const float* eb1 = (const float*)d_in[12];
    const float* eW2 = (const float*)d_in[13];
    const float* eb2 = (const float*)d_in[14];
    const float* eg  = (const float*)d_in[15];
    const float* ebn = (const float*)d_in[16];
    const float* nW1 = (const float*)d_in[17];
    const float* nb1 = (const float*)d_in[18];
    const float* nW2 = (const float*)d_in[19];
    const float* nb2 = (const float*)d_in[20];
    const float* ng  = (const float*)d_in[21];
    const float* nbn = (const float*)d_in[22];
    const float* gW1 = (const float*)d_in[23];
    const float* gb1 = (const float*)d_in[24];
    const float* gW2 = (const float*)d_in[25];
    const float* gb2 = (const float*)d_in[26];
    const float* gg  = (const float*)d_in[27];
    const float* gbn = (const float*)d_in[28];
    const float* aW1 = (const float*)d_in[29];
    const float* ab1 = (const float*)d_in[30];
    const float* aW2 = (const float*)d_in[31];
    const float* ab2 = (const float*)d_in[32];
    const float* cW1 = (const float*)d_in[33];
    const float* cb1 = (const float*)d_in[34];
    const float* cW2 = (const float*)d_in[35];
    const float* cb2 = (const float*)d_in[36];

    const int* srcI = ei;
    const int* dstI = ei + En;

    float* ws     = (float*)d_ws;
    float* hx     = ws;                              // N*128
    float* he     = hx + (size_t)Nn * H;             // E*128
    float* agg    = he + (size_t)En * H;             // N*128
    float* deg    = agg + (size_t)Nn * H;            // N   (becomes 1/deg)
    float* u      = deg + Nn;                        // 64*128
    float* nmean  = u + Gn * H;                      // 64*128
    float* emean  = nmean + Gn * H;                  // 64*128
    float* logits = emean + Gn * H;                  // N
    int*   ebatch = (int*)(logits + Nn);             // E

    float* outp = (float*)d_out;

    // input projections + constants
    proj_relu<64><<<Nn / BM, 256, 0, stream>>>(x, Wn, bn_, hx);
    proj_relu<32><<<En / BM, 256, 0, stream>>>(ea, We, be_, he);
    init_u_k<<<(Gn * H) / 256, 256, 0, stream>>>(u, u0);
    make_ebatch_k<<<En / 256, 256, 0, stream>>>(srcI, batch, ebatch);
    hipMemsetAsync(deg, 0, Nn * sizeof(float), stream);
    count_deg_k<<<En / 256, 256, 0, stream>>>(dstI, deg);
    inv_deg_k<<<Nn / 256, 256, 0, stream>>>(deg);

    for (int l = 0; l < 2; ++l) {
        // edge update: e = LN-MLP([x[src] || x[dst] || e || u[ebatch]])   (in-place on he)
        fused_mlp_ln<4><<<En / BM, 256, 0, stream>>>(
            hx, srcI, nullptr,
            hx, dstI, nullptr,
            he, nullptr, nullptr,
            u,  ebatch, nullptr,
            eW1, eb1, eW2, eb2, eg, ebn, he);
        // agg = segment_sum(e, dst) ; divided by deg during node gather
        hipMemsetAsync(agg, 0, (size_t)Nn * H * sizeof(float), stream);
        scatter_add_k<<<(En * 32) / 256, 256, 0, stream>>>(he, dstI, agg);
        // node update: x = LN-MLP([x || agg/deg || u[batch]])             (in-place on hx)
        fused_mlp_ln<3><<<Nn / BM, 256, 0, stream>>>(
            hx, nullptr, nullptr,
            agg, nullptr, deg,
            u,  batch, nullptr,
            nullptr, nullptr, nullptr,
            nW1, nb1, nW2, nb2, ng, nbn, hx);
        // global update: u = LN-MLP([u || mean(x) || mean(e)])            (in-place on u)
        hipMemsetAsync(nmean, 0, Gn * H * sizeof(float), stream);
        hipMemsetAsync(emean, 0, Gn * H * sizeof(float), stream);
        pool_mean_k<<<Gn * 4, 256, 0, stream>>>(hx, nmean, Pn, 4, 1.f / Pn);
        pool_mean_k<<<Gn * 16, 256, 0, stream>>>(he, emean, EPGn, 16, 1.f / EPGn);
        fused_mlp_ln<3><<<1, 256, 0, stream>>>(
            u, nullptr, nullptr,
            nmean, nullptr, nullptr,
            emean, nullptr, nullptr,
            nullptr, nullptr, nullptr,
            gW1, gb1, gW2, gb2, gg, gbn, u);
    }

    // action head -> logits[N]; per-graph argmax/logprob/entropy; value head
    head_mlp<<<Nn / BM, 256, 0, stream>>>(hx, aW1, ab1, aW2, ab2, logits);
    softmax_head_k<<<Gn, 256, 0, stream>>>(logits, outp);
    head_mlp<<<1, 256, 0, stream>>>(u, cW1, cb1, cW2, cb2, outp + 3 * Gn);
}

// Round 2
// 1566.811 us; speedup vs baseline: 1.6780x; 1.6780x over previous
//
#include <hip/hip_runtime.h>
#include <cstddef>

namespace {

constexpr int Gn  = 64;
constexpr int Pn  = 512;
constexpr int EPGn= 4096;
constexpr int Nn  = Gn * Pn;    // 32768 nodes
constexpr int En  = Gn * EPGn;  // 262144 edges
constexpr int H   = 128;

constexpr int BM = 64, BK = 32, BN = 128;
constexpr int LDA = BK + 4;

typedef __bf16 bf16_t;
typedef bf16_t bf16x8 __attribute__((ext_vector_type(8)));
typedef float  f32x4  __attribute__((ext_vector_type(4)));

__device__ __forceinline__ float4 ld4(const float* p) { return *reinterpret_cast<const float4*>(p); }
__device__ __forceinline__ void st4(float* p, const float4 v) { *reinterpret_cast<float4*>(p) = v; }
__device__ __forceinline__ f32x4 mfma16(bf16x8 a, bf16x8 b, f32x4 c) {
    return __builtin_amdgcn_mfma_f32_16x16x32_bf16(a, b, c, 0, 0, 0);
}

// ---------------------------------------------------------------------------
// Weight prep: fp32 W[K][128] -> bf16 hi/lo in MFMA B-fragment-major layout.
// Fragment tile = 32k x 16n. Element (k,n) lives at
//   idx = (((k>>5)*8 + (n>>4))*64 + ((k>>3)&3)*16 + (n&15))*8 + (k&7)
// so a lane's 8 B-values (k=(lane>>4)*8+j, n=lane&15) are 16B contiguous.
// ---------------------------------------------------------------------------
__global__ void prep_wfrag(const float* __restrict__ W, bf16_t* __restrict__ Bh,
                           bf16_t* __restrict__ Bl)
{
    const int i = blockIdx.x * 256 + threadIdx.x;   // i < K*128
    const int k = i >> 7, n = i & 127;
    const float v = W[i];
    const bf16_t h = (bf16_t)v;
    const bf16_t l = (bf16_t)(v - (float)h);
    const int idx = ((((k >> 5) * 8) + (n >> 4)) * 64 + ((k >> 3) & 3) * 16 + (n & 15)) * 8 + (k & 7);
    Bh[idx] = h; Bl[idx] = l;
}

// ---------------------------------------------------------------------------
// Stage one 64row x 32k chunk of the gathered/concat A matrix into LDS,
// split fp32 -> bf16 hi/lo, fragment-major: dst[(kg*64 + row)*8 + j].
// thread t: row = t&63, kg = t>>6.
// ---------------------------------------------------------------------------
__device__ __forceinline__ void stage_chunk(
    const float* p0, const int* i0, const float* s0,
    const float* p1, const int* i1, const float* s1,
    const float* p2, const int* i2, const float* s2,
    const float* p3, const int* i3, const float* s3,
    int kc, int row0, int t, bf16_t* __restrict__ dH, bf16_t* __restrict__ dL)
{
    const int r  = t & 63;
    const int kg = t >> 6;
    const int seg = kc >> 2;
    const float* p; const int* ix; const float* sc;
    if (seg == 0)      { p = p0; ix = i0; sc = s0; }
    else if (seg == 1) { p = p1; ix = i1; sc = s1; }
    else if (seg == 2) { p = p2; ix = i2; sc = s2; }
    else               { p = p3; ix = i3; sc = s3; }
    const int grow = row0 + r;
    const int sr = ix ? ix[grow] : grow;
    const float* sp = p + (size_t)sr * H + (kc & 3) * 32 + kg * 8;
    float4 a = ld4(sp), b = ld4(sp + 4);
    if (sc) {
        const float s = sc[sr];
        a.x *= s; a.y *= s; a.z *= s; a.w *= s;
        b.x *= s; b.y *= s; b.z *= s; b.w *= s;
    }
    const float v[8] = {a.x, a.y, a.z, a.w, b.x, b.y, b.z, b.w};
    bf16x8 hv, lv;
#pragma unroll
    for (int j = 0; j < 8; ++j) {
        const bf16_t h = (bf16_t)v[j];
        hv[j] = h;
        lv[j] = (bf16_t)(v[j] - (float)h);
    }
    *reinterpret_cast<bf16x8*>(dH + (kg * 64 + r) * 8) = hv;
    *reinterpret_cast<bf16x8*>(dL + (kg * 64 + r) * 8) = lv;
}

__device__ __forceinline__ void loadB(const bf16_t* __restrict__ Wh, const bf16_t* __restrict__ Wl,
                                      int kc, int wn, int lane, bf16x8* Bh, bf16x8* Bl)
{
#pragma unroll
    for (int nt = 0; nt < 4; ++nt) {
        const size_t idx = (size_t)(((kc * 8) + wn * 4 + nt) * 64 + lane) * 8;
        Bh[nt] = *reinterpret_cast<const bf16x8*>(Wh + idx);
        Bl[nt] = *reinterpret_cast<const bf16x8*>(Wl + idx);
    }
}

// ---------------------------------------------------------------------------
// MFMA fused 2-layer MLP + LN, bf16x3 (split-fp32) precision.
// Block: 256 thr = 4 waves as 2(wm) x 2(wn); BM=64 rows, BN=128 cols.
// Wave tile: 32 rows (2 m-tiles) x 64 cols (4 n-tiles), 16x16x32 MFMA.
// Phase1: K = NSEG*128 staged from gathered fp32 sources (split on the fly).
// Phase2: hidden (64x128) relu'd/split into LDS frag layout, @ W2, then LN.
// ---------------------------------------------------------------------------
template<int NSEG>
__global__ __launch_bounds__(256, 2)
void mfma_mlp_ln(const float* __restrict__ p0, const int* __restrict__ i0, const float* __restrict__ s0,
                 const float* __restrict__ p1, const int* __restrict__ i1, const float* __restrict__ s1,
                 const float* __restrict__ p2, const int* __restrict__ i2, const float* __restrict__ s2,
                 const float* __restrict__ p3, const int* __restrict__ i3, const float* __restrict__ s3,
                 const bf16_t* __restrict__ W1h, const bf16_t* __restrict__ W1l,
                 const bf16_t* __restrict__ W2h, const bf16_t* __restrict__ W2l,
                 const float* __restrict__ b1, const float* __restrict__ b2,
                 const float* __restrict__ gam, const float* __restrict__ bet,
                 float* __restrict__ outp)
{
    __shared__ bf16_t sA[2][2][4 * 64 * 8];   // [buf][hi/lo][kg][row][j]  16KB
    __shared__ bf16_t sH[2][16 * 64 * 8];     // [hi/lo][k>>3][row][j]     32KB
    __shared__ float  redS[2][64], redQ[2][64];

    const int t = threadIdx.x;
    const int lane = t & 63;
    const int wv = t >> 6;
    const int wn = wv & 1, wm = wv >> 1;
    const int l15 = lane & 15, l4 = lane >> 4;
    const int row0 = blockIdx.x * 64;

    f32x4 acc[2][4];
#pragma unroll
    for (int mt = 0; mt < 2; ++mt)
#pragma unroll
        for (int nt = 0; nt < 4; ++nt) acc[mt][nt] = (f32x4)0.f;

    constexpr int NC1 = NSEG * 4;

    bf16x8 Bh[4], Bl[4], Bh2[4], Bl2[4];
    stage_chunk(p0,i0,s0, p1,i1,s1, p2,i2,s2, p3,i3,s3, 0, row0, t, sA[0][0], sA[0][1]);
    loadB(W1h, W1l, 0, wn, lane, Bh, Bl);

    int buf = 0;
#pragma unroll 1
    for (int kc = 0; kc < NC1; ++kc) {
        __syncthreads();
        const bool pre = (kc + 1 < NC1);
        if (pre) {
            stage_chunk(p0,i0,s0, p1,i1,s1, p2,i2,s2, p3,i3,s3, kc + 1, row0, t,
                        sA[buf ^ 1][0], sA[buf ^ 1][1]);
            loadB(W1h, W1l, kc + 1, wn, lane, Bh2, Bl2);
        }
        const bf16_t* baseH = sA[buf][0];
        const bf16_t* baseL = sA[buf][1];
#pragma unroll
        for (int mt = 0; mt < 2; ++mt) {
            const int ro = wm * 32 + mt * 16 + l15;
            const bf16x8 Ah = *reinterpret_cast<const bf16x8*>(baseH + (l4 * 64 + ro) * 8);
            const bf16x8 Al = *reinterpret_cast<const bf16x8*>(baseL + (l4 * 64 + ro) * 8);
#pragma unroll
            for (int nt = 0; nt < 4; ++nt) {
                acc[mt][nt] = mfma16(Al, Bh[nt], acc[mt][nt]);
                acc[mt][nt] = mfma16(Ah, Bl[nt], acc[mt][nt]);
                acc[mt][nt] = mfma16(Ah, Bh[nt], acc[mt][nt]);
            }
        }
        if (pre) {
#pragma unroll
            for (int q = 0; q < 4; ++q) { Bh[q] = Bh2[q]; Bl[q] = Bl2[q]; }
        }
        buf ^= 1;
    }

    // ---- transition: hidden = relu(acc + b1), split -> sH frag layout ----
#pragma unroll
    for (int mt = 0; mt < 2; ++mt)
#pragma unroll
        for (int nt = 0; nt < 4; ++nt) {
            const int col = wn * 64 + nt * 16 + l15;
            const float bb = b1[col];
#pragma unroll
            for (int r2 = 0; r2 < 4; ++r2) {
                const int rloc = wm * 32 + mt * 16 + l4 * 4 + r2;
                float v = acc[mt][nt][r2] + bb;
                v = v > 0.f ? v : 0.f;
                const bf16_t h = (bf16_t)v;
                const int sidx = (col >> 3) * 512 + rloc * 8 + (col & 7);
                sH[0][sidx] = h;
                sH[1][sidx] = (bf16_t)(v - (float)h);
                acc[mt][nt][r2] = 0.f;
            }
        }
    __syncthreads();

    // ---- phase 2: out = hidden @ W2 ----
    loadB(W2h, W2l, 0, wn, lane, Bh, Bl);
#pragma unroll 1
    for (int kc = 0; kc < 4; ++kc) {
        if (kc + 1 < 4) loadB(W2h, W2l, kc + 1, wn, lane, Bh2, Bl2);
#pragma unroll
        for (int mt = 0; mt < 2; ++mt) {
            const int ro = wm * 32 + mt * 16 + l15;
            const bf16x8 Ah = *reinterpret_cast<const bf16x8*>(sH[0] + ((kc * 4 + l4) * 64 + ro) * 8);
            const bf16x8 Al = *reinterpret_cast<const bf16x8*>(sH[1] + ((kc * 4 + l4) * 64 + ro) * 8);
#pragma unroll
            for (int nt = 0; nt < 4; ++nt) {
                acc[mt][nt] = mfma16(Al, Bh[nt], acc[mt][nt]);
                acc[mt][nt] = mfma16(Ah, Bl[nt], acc[mt][nt]);
                acc[mt][nt] = mfma16(Ah, Bh[nt], acc[mt][nt]);
            }
        }
        if (kc + 1 < 4) {
#pragma unroll
            for (int q = 0; q < 4; ++q) { Bh[q] = Bh2[q]; Bl[q] = Bl2[q]; }
        }
    }

    // ---- epilogue: bias2 + LayerNorm + affine ----
    float bb2[4], ggv[4], btv[4];
#pragma unroll
    for (int nt = 0; nt < 4; ++nt) {
        const int col = wn * 64 + nt * 16 + l15;
        bb2[nt] = b2[col]; ggv[nt] = gam[col]; btv[nt] = bet[col];
    }
#pragma unroll
    for (int mt = 0; mt < 2; ++mt)
#pragma unroll
        for (int r2 = 0; r2 < 4; ++r2) {
            float s = 0.f, q = 0.f;
#pragma unroll
            for (int nt = 0; nt < 4; ++nt) {
                const float v = acc[mt][nt][r2] + bb2[nt];
                s += v; q += v * v;
            }
            s += __shfl_xor(s, 1, 16); s += __shfl_xor(s, 2, 16);
            s += __shfl_xor(s, 4, 16); s += __shfl_xor(s, 8, 16);
            q += __shfl_xor(q, 1, 16); q += __shfl_xor(q, 2, 16);
            q += __shfl_xor(q, 4, 16); q += __shfl_xor(q, 8, 16);
            if (l15 == 0) {
                const int row = wm * 32 + mt * 16 + l4 * 4 + r2;
                redS[wn][row] = s; redQ[wn][row] = q;
            }
        }
    __syncthreads();
#pragma unroll
    for (int mt = 0; mt < 2; ++mt)
#pragma unroll
        for (int r2 = 0; r2 < 4; ++r2) {
            const int row = wm * 32 + mt * 16 + l4 * 4 + r2;
            const float S = redS[0][row] + redS[1][row];
            const float Q = redQ[0][row] + redQ[1][row];
            const float mean = S * (1.f / 128.f);
            const float var  = Q * (1.f / 128.f) - mean * mean;
            const float rstd = rsqrtf(var + 1e-5f);
            float* op = outp + (size_t)(row0 + row) * H;
#pragma unroll
            for (int nt = 0; nt < 4; ++nt) {
                const int col = wn * 64 + nt * 16 + l15;
                const float v = acc[mt][nt][r2] + bb2[nt];
                op[col] = (v - mean) * rstd * ggv[nt] + btv[nt];
            }
        }
}

// ---------------------------------------------------------------------------
// Input projection: out = relu(in[rows,K] @ W[K,128] + b), K in {64,32} (fp32)
// ---------------------------------------------------------------------------
template<int K>
__global__ __launch_bounds__(256, 2)
void proj_relu(const float* __restrict__ in, const float* __restrict__ W,
               const float* __restrict__ b, float* __restrict__ out)
{
    constexpr int LDAP = K + 4;
    __shared__ float sA[BM * LDAP];
    __shared__ float sWp[K * BN];

    const int tid = threadIdx.x;
    const int rg = tid >> 4, cg = tid & 15;
    const int m0 = rg * 4, n0 = cg * 8;
    const int row0 = blockIdx.x * BM;

    if constexpr (K == 64) {
        const int lr = tid >> 2, lc = (tid & 3) * 16;
        const float* srcp = in + (size_t)(row0 + lr) * K + lc;
#pragma unroll
        for (int q = 0; q < 16; q += 4) st4(&sA[lr * LDAP + lc + q], ld4(srcp + q));
        const int wrk = tid >> 2, wck = (tid & 3) * 32;
        const float* wsp = W + (size_t)wrk * BN + wck;
#pragma unroll
        for (int q = 0; q < 32; q += 4) st4(&sWp[wrk * BN + wck + q], ld4(wsp + q));
    } else {
        const int lr = tid >> 2, lc = (tid & 3) * 8;
        const float* srcp = in + (size_t)(row0 + lr) * K + lc;
        st4(&sA[lr * LDAP + lc],     ld4(srcp));
        st4(&sA[lr * LDAP + lc + 4], ld4(srcp + 4));
        const int wrk = tid >> 3, wck = (tid & 7) * 16;
        const float* wsp = W + (size_t)wrk * BN + wck;
#pragma unroll
        for (int q = 0; q < 16; q += 4) st4(&sWp[wrk * BN + wck + q], ld4(wsp + q));
    }
    __syncthreads();

    float acc[4][8];
#pragma unroll
    for (int i = 0; i < 4; ++i)
#pragma unroll
        for (int j = 0; j < 8; ++j) acc[i][j] = 0.f;

#pragma unroll 8
    for (int k = 0; k < K; ++k) {
        float a[4];
#pragma unroll
        for (int i = 0; i < 4; ++i) a[i] = sA[(m0 + i) * LDAP + k];
        const float4 wA = ld4(&sWp[k * BN + n0]);
        const float4 wB = ld4(&sWp[k * BN + n0 + 4]);
        const float w[8] = {wA.x, wA.y, wA.z, wA.w, wB.x, wB.y, wB.z, wB.w};
#pragma unroll
        for (int i = 0; i < 4; ++i)
#pragma unroll
            for (int j = 0; j < 8; ++j)
                acc[i][j] = fmaf(a[i], w[j], acc[i][j]);
    }

    const float4 bA = ld4(&b[n0]), bB = ld4(&b[n0 + 4]);
    const float bb[8] = {bA.x, bA.y, bA.z, bA.w, bB.x, bB.y, bB.z, bB.w};
#pragma unroll
    for (int i = 0; i < 4; ++i) {
        float o[8];
#pragma unroll
        for (int j = 0; j < 8; ++j) {
            const float v = acc[i][j] + bb[j];
            o[j] = v > 0.f ? v : 0.f;
        }
        float* op = out + (size_t)(row0 + m0 + i) * H + n0;
        st4(op,     make_float4(o[0], o[1], o[2], o[3]));
        st4(op + 4, make_float4(o[4], o[5], o[6], o[7]));
    }
}

// ---------------------------------------------------------------------------
// Head: out[row] = relu(in[row,:] @ W1 + b1) . w2 + b2[0]   (fp32 for logits)
// ---------------------------------------------------------------------------
__global__ __launch_bounds__(256, 2)
void head_mlp(const float* __restrict__ in, const float* __restrict__ W1,
              const float* __restrict__ b1, const float* __restrict__ w2,
              const float* __restrict__ b2, float* __restrict__ outp)
{
    __shared__ float sA[BM * LDA];
    __shared__ float sW[BK * BN];

    const int tid = threadIdx.x;
    const int rg = tid >> 4, cg = tid & 15;
    const int m0 = rg * 4, n0 = cg * 8;
    const int row0 = blockIdx.x * BM;
    const int lr = tid >> 2, lc = (tid & 3) * 8;
    const int wr = tid >> 3, wc = (tid & 7) * 16;

    float acc[4][8];
#pragma unroll
    for (int i = 0; i < 4; ++i)
#pragma unroll
        for (int j = 0; j < 8; ++j) acc[i][j] = 0.f;

#pragma unroll 1
    for (int kc = 0; kc < 4; ++kc) {
        const int koff = kc * 32;
        const float* srcp = in + (size_t)(row0 + lr) * H + koff + lc;
        st4(&sA[lr * LDA + lc],     ld4(srcp));
        st4(&sA[lr * LDA + lc + 4], ld4(srcp + 4));
        const float* wsrc = W1 + (size_t)koff * BN + wr * BN + wc;
        st4(&sW[wr * BN + wc],      ld4(wsrc));
        st4(&sW[wr * BN + wc + 4],  ld4(wsrc + 4));
        st4(&sW[wr * BN + wc + 8],  ld4(wsrc + 8));
        st4(&sW[wr * BN + wc + 12], ld4(wsrc + 12));
        __syncthreads();
#pragma unroll
        for (int kk = 0; kk < BK; ++kk) {
            float a[4];
#pragma unroll
            for (int i = 0; i < 4; ++i) a[i] = sA[(m0 + i) * LDA + kk];
            const float4 wA = ld4(&sW[kk * BN + n0]);
            const float4 wB = ld4(&sW[kk * BN + n0 + 4]);
            const float w[8] = {wA.x, wA.y, wA.z, wA.w, wB.x, wB.y, wB.z, wB.w};
#pragma unroll
            for (int i = 0; i < 4; ++i)
#pragma unroll
                for (int j = 0; j < 8; ++j)
                    acc[i][j] = fmaf(a[i], w[j], acc[i][j]);
        }
        __syncthreads();
    }

    const float4 bA = ld4(&b1[n0]),  bB = ld4(&b1[n0 + 4]);
    const float4 vA = ld4(&w2[n0]),  vB = ld4(&w2[n0 + 4]);
    const float bb[8] = {bA.x, bA.y, bA.z, bA.w, bB.x, bB.y, bB.z, bB.w};
    const float vv[8] = {vA.x, vA.y, vA.z, vA.w, vB.x, vB.y, vB.z, vB.w};
#pragma unroll
    for (int i = 0; i < 4; ++i) {
        float p = 0.f;
#pragma unroll
        for (int j = 0; j < 8; ++j) {
            float h = acc[i][j] + bb[j];
            h = h > 0.f ? h : 0.f;
            p = fmaf(h, vv[j], p);
        }
        p += __shfl_xor(p, 1, 16); p += __shfl_xor(p, 2, 16);
        p += __shfl_xor(p, 4, 16); p += __shfl_xor(p, 8, 16);
        if (cg == 0) outp[row0 + m0 + i] = p + b2[0];
    }
}

// ---------------------------------------------------------------------------
// small utility kernels
// ---------------------------------------------------------------------------
__global__ void init_u_k(float* __restrict__ u, const float* __restrict__ u0)
{
    const int idx = blockIdx.x * 256 + threadIdx.x;
    u[idx] = u0[idx & (H - 1)];
}

__global__ void make_ebatch_k(const int* __restrict__ src, const int* __restrict__ batch,
                              int* __restrict__ eb)
{
    const int i = blockIdx.x * 256 + threadIdx.x;
    eb[i] = batch[src[i]];
}

__global__ void count_deg_k(const int* __restrict__ dst, float* __restrict__ deg)
{
    const int i = blockIdx.x * 256 + threadIdx.x;
    atomicAdd(&deg[dst[i]], 1.0f);
}

__global__ void inv_deg_k(float* __restrict__ deg)
{
    const int i = blockIdx.x * 256 + threadIdx.x;
    deg[i] = 1.0f / fmaxf(deg[i], 1.0f);
}

__global__ void scatter_add_k(const float* __restrict__ e, const int* __restrict__ dst,
                              float* __restrict__ agg)
{
    const int idx = blockIdx.x * 256 + threadIdx.x;   // < E*32
    const int edge = idx >> 5;
    const int q = (idx & 31) * 4;
    const float4 v = ld4(&e[(size_t)edge * H + q]);
    float* a = &agg[(size_t)dst[edge] * H + q];
    atomicAdd(a + 0, v.x); atomicAdd(a + 1, v.y);
    atomicAdd(a + 2, v.z); atomicAdd(a + 3, v.w);
}

__global__ void pool_mean_k(const float* __restrict__ in, float* __restrict__ out,
                            int rpg, int splits, float scale)
{
    const int g  = blockIdx.x / splits;
    const int sp = blockIdx.x % splits;
    const int rpb = rpg / splits;
    const int tid = threadIdx.x;
    const int col = tid & (H - 1);
    const int half = tid >> 7;
    const size_t base = ((size_t)g * rpg + (size_t)sp * rpb) * H;
    float s = 0.f;
    const int r0 = half * (rpb / 2), r1 = r0 + rpb / 2;
    for (int r = r0; r < r1; ++r) s += in[base + (size_t)r * H + col];
    __shared__ float red[256];
    red[tid] = s;
    __syncthreads();
    if (half == 0) atomicAdd(&out[g * H + col], (red[col] + red[128 + col]) * scale);
}

__global__ void softmax_head_k(const float* __restrict__ logits, float* __restrict__ outp)
{
    const int g = blockIdx.x;
    const int tid = threadIdx.x;
    const float* lg = logits + (size_t)g * Pn;
    const float v0 = lg[tid], v1 = lg[tid + 256];
    float bv; int bi;
    if (v1 > v0) { bv = v1; bi = tid + 256; } else { bv = v0; bi = tid; }

    __shared__ float sv[256];
    __shared__ int   si[256];
    sv[tid] = bv; si[tid] = bi;
    __syncthreads();
    for (int s = 128; s > 0; s >>= 1) {
        if (tid < s) {
            const float ov = sv[tid + s]; const int oi = si[tid + s];
            if (ov > sv[tid] || (ov == sv[tid] && oi < si[tid])) { sv[tid] = ov; si[tid] = oi; }
        }
        __syncthreads();
    }
    const float mx = sv[0];
    const int ai = si[0];
    __syncthreads();

    const float d0 = v0 - mx, d1 = v1 - mx;
    const float e0 = __expf(d0), e1 = __expf(d1);
    __shared__ float ss[256];
    __shared__ float st[256];
    ss[tid] = e0 + e1;
    st[tid] = e0 * d0 + e1 * d1;
    __syncthreads();
    for (int s = 128; s > 0; s >>= 1) {
        if (tid < s) { ss[tid] += ss[tid + s]; st[tid] += st[tid + s]; }
        __syncthreads();
    }
    if (tid == 0) {
        const float S = ss[0];
        const float logS = logf(S);
        outp[g]            = (float)ai;
        outp[Gn + g]       = -logS;
        outp[2 * Gn + g]   = logS - st[0] / S;
    }
}

} // namespace

extern "C" void kernel_launch(void* const* d_in, const int* in_sizes, int n_in,
                              void* d_out, int out_size, void* d_ws, size_t ws_size,
                              hipStream_t stream)
{
    (void)in_sizes; (void)n_in; (void)out_size; (void)ws_size;

    const float* x     = (const float*)d_in[0];
    const float* ea    = (const float*)d_in[1];
    const int*   ei    = (const int*)d_in[2];
    const int*   batch = (const int*)d_in[3];
    const float* Wn  = (const float*)d_in[6];
    const float* bn_ = (const float*)d_in[7];
    const float* We  = (const float*)d_in[8];
    const float* be_ = (const float*)d_in[9];
    const float* u0  = (const float*)d_in[10];
    const float* eW1 = (const float*)d_in[11];
    const float* eb1 = (const float*)d_in[12];
    const float* eW2 = (const float*)d_in[13];
    const float* eb2 = (const float*)d_in[14];
    const float* eg  = (const float*)d_in[15];
    const float* ebn = (const float*)d_in[16];
    const float* nW1 = (const float*)d_in[17];
    const float* nb1 = (const float*)d_in[18];
    const float* nW2 = (const float*)d_in[19];
    const float* nb2 = (const float*)d_in[20];
    const float* ng  = (const float*)d_in[21];
    const float* nbn = (const float*)d_in[22];
    const float* gW1 = (const float*)d_in[23];
    const float* gb1 = (const float*)d_in[24];
    const float* gW2 = (const float*)d_in[25];
    const float* gb2 = (const float*)d_in[26];
    const float* gg  = (const float*)d_in[27];
    const float* gbn = (const float*)d_in[28];
    const float* aW1 = (const float*)d_in[29];
    const float* ab1 = (const float*)d_in[30];
    const float* aW2 = (const float*)d_in[31];
    const float* ab2 = (const float*)d_in[32];
    const float* cW1 = (const float*)d_in[33];
    const float* cb1 = (const float*)d_in[34];
    const float* cW2 = (const float*)d_in[35];
    const float* cb2 = (const float*)d_in[36];

    const int* srcI = ei;
    const int* dstI = ei + En;

    float* ws     = (float*)d_ws;
    float* hx     = ws;                              // N*128
    float* he     = hx + (size_t)Nn * H;             // E*128
    float* agg    = he + (size_t)En * H;             // N*128
    float* deg    = agg + (size_t)Nn * H;            // N (1/deg)
    float* u      = deg + Nn;                        // 64*128
    float* nmean  = u + Gn * H;
    float* emean  = nmean + Gn * H;
    float* logits = emean + Gn * H;                  // N
    int*   ebatch = (int*)(logits + Nn);             // E ints
    // bf16 weight-fragment arrays after the fp32/int region
    bf16_t* frag = (bf16_t*)(ebatch + En);
    bf16_t* eW1h = frag;              bf16_t* eW1l = eW1h + 512 * 128;   frag += 2 * 512 * 128;
    bf16_t* eW2h = frag;              bf16_t* eW2l = eW2h + 128 * 128;   frag += 2 * 128 * 128;
    bf16_t* nW1h = frag;              bf16_t* nW1l = nW1h + 384 * 128;   frag += 2 * 384 * 128;
    bf16_t* nW2h = frag;              bf16_t* nW2l = nW2h + 128 * 128;   frag += 2 * 128 * 128;
    bf16_t* gW1h = frag;              bf16_t* gW1l = gW1h + 384 * 128;   frag += 2 * 384 * 128;
    bf16_t* gW2h = frag;              bf16_t* gW2l = gW2h + 128 * 128;

    float* outp = (float*)d_out;

    // weight prep (fragment-major bf16 hi/lo)
    prep_wfrag<<<(512 * 128) / 256, 256, 0, stream>>>(eW1, eW1h, eW1l);
    prep_wfrag<<<(128 * 128) / 256, 256, 0, stream>>>(eW2, eW2h, eW2l);
    prep_wfrag<<<(384 * 128) / 256, 256, 0, stream>>>(nW1, nW1h, nW1l);
    prep_wfrag<<<(128 * 128) / 256, 256, 0, stream>>>(nW2, nW2h, nW2l);
    prep_wfrag<<<(384 * 128) / 256, 256, 0, stream>>>(gW1, gW1h, gW1l);
    prep_wfrag<<<(128 * 128) / 256, 256, 0, stream>>>(gW2, gW2h, gW2l);

    // input projections + constants
    proj_relu<64><<<Nn / BM, 256, 0, stream>>>(x, Wn, bn_, hx);
    proj_relu<32><<<En / BM, 256, 0, stream>>>(ea, We, be_, he);
    init_u_k<<<(Gn * H) / 256, 256, 0, stream>>>(u, u0);
    make_ebatch_k<<<En / 256, 256, 0, stream>>>(srcI, batch, ebatch);
    hipMemsetAsync(deg, 0, Nn * sizeof(float), stream);
    count_deg_k<<<En / 256, 256, 0, stream>>>(dstI, deg);
    inv_deg_k<<<Nn / 256, 256, 0, stream>>>(deg);

    for (int l = 0; l < 2; ++l) {
        // edge update (in-place on he)
        mfma_mlp_ln<4><<<En / 64, 256, 0, stream>>>(
            hx, srcI, nullptr,
            hx, dstI, nullptr,
            he, nullptr, nullptr,
            u,  ebatch, nullptr,
            eW1h, eW1l, eW2h, eW2l, eb1, eb2, eg, ebn, he);
        // agg = segment_sum(e, dst); /deg applied at gather
        hipMemsetAsync(agg, 0, (size_t)Nn * H * sizeof(float), stream);
        scatter_add_k<<<(En * 32) / 256, 256, 0, stream>>>(he, dstI, agg);
        // node update (in-place on hx)
        mfma_mlp_ln<3><<<Nn / 64, 256, 0, stream>>>(
            hx, nullptr, nullptr,
            agg, nullptr, deg,
            u,  batch, nullptr,
            nullptr, nullptr, nullptr,
            nW1h, nW1l, nW2h, nW2l, nb1, nb2, ng, nbn, hx);
        // global update (in-place on u)
        hipMemsetAsync(nmean, 0, Gn * H * sizeof(float), stream);
        hipMemsetAsync(emean, 0, Gn * H * sizeof(float), stream);
        pool_mean_k<<<Gn * 4, 256, 0, stream>>>(hx, nmean, Pn, 4, 1.f / Pn);
        pool_mean_k<<<Gn * 16, 256, 0, stream>>>(he, emean, EPGn, 16, 1.f / EPGn);
        mfma_mlp_ln<3><<<1, 256, 0, stream>>>(
            u, nullptr, nullptr,
            nmean, nullptr, nullptr,
            emean, nullptr, nullptr,
            nullptr, nullptr, nullptr,
            gW1h, gW1l, gW2h, gW2l, gb1, gb2, gg, gbn, u);
    }

    head_mlp<<<Nn / BM, 256, 0, stream>>>(hx, aW1, ab1, aW2, ab2, logits);
    softmax_head_k<<<Gn, 256, 0, stream>>>(logits, outp);
    head_mlp<<<1, 256, 0, stream>>>(u, cW1, cb1, cW2, cb2, outp + 3 * Gn);
}

// Round 3
// 761.549 us; speedup vs baseline: 3.4524x; 2.0574x over previous
//
#include <hip/hip_runtime.h>
#include <cstddef>

namespace {

constexpr int Gn  = 64;
constexpr int Pn  = 512;
constexpr int EPGn= 4096;
constexpr int Nn  = Gn * Pn;    // 32768 nodes
constexpr int En  = Gn * EPGn;  // 262144 edges
constexpr int H   = 128;

constexpr int BM = 64, BK = 32, BN = 128;
constexpr int LDA = BK + 4;

typedef __bf16 bf16_t;
typedef bf16_t bf16x8 __attribute__((ext_vector_type(8)));
typedef float  f32x4  __attribute__((ext_vector_type(4)));

__device__ __forceinline__ float4 ld4(const float* p) { return *reinterpret_cast<const float4*>(p); }
__device__ __forceinline__ void st4(float* p, const float4 v) { *reinterpret_cast<float4*>(p) = v; }
__device__ __forceinline__ f32x4 mfma16(bf16x8 a, bf16x8 b, f32x4 c) {
    return __builtin_amdgcn_mfma_f32_16x16x32_bf16(a, b, c, 0, 0, 0);
}

// ---------------------------------------------------------------------------
// Weight prep: fp32 W[K][128] -> bf16 hi/lo in MFMA B-fragment-major layout.
// ---------------------------------------------------------------------------
__global__ void prep_wfrag(const float* __restrict__ W, bf16_t* __restrict__ Bh,
                           bf16_t* __restrict__ Bl)
{
    const int i = blockIdx.x * 256 + threadIdx.x;   // i < K*128
    const int k = i >> 7, n = i & 127;
    const float v = W[i];
    const bf16_t h = (bf16_t)v;
    const bf16_t l = (bf16_t)(v - (float)h);
    const int idx = ((((k >> 5) * 8) + (n >> 4)) * 64 + ((k >> 3) & 3) * 16 + (n & 15)) * 8 + (k & 7);
    Bh[idx] = h; Bl[idx] = l;
}

// ---------------------------------------------------------------------------
// Staging for the fused MFMA MLP (same as R2).
// ---------------------------------------------------------------------------
__device__ __forceinline__ void stage_chunk(
    const float* p0, const int* i0, const float* s0,
    const float* p1, const int* i1, const float* s1,
    const float* p2, const int* i2, const float* s2,
    const float* p3, const int* i3, const float* s3,
    int kc, int row0, int t, bf16_t* __restrict__ dH, bf16_t* __restrict__ dL)
{
    const int r  = t & 63;
    const int kg = t >> 6;
    const int seg = kc >> 2;
    const float* p; const int* ix; const float* sc;
    if (seg == 0)      { p = p0; ix = i0; sc = s0; }
    else if (seg == 1) { p = p1; ix = i1; sc = s1; }
    else if (seg == 2) { p = p2; ix = i2; sc = s2; }
    else               { p = p3; ix = i3; sc = s3; }
    const int grow = row0 + r;
    const int sr = ix ? ix[grow] : grow;
    const float* sp = p + (size_t)sr * H + (kc & 3) * 32 + kg * 8;
    float4 a = ld4(sp), b = ld4(sp + 4);
    if (sc) {
        const float s = sc[sr];
        a.x *= s; a.y *= s; a.z *= s; a.w *= s;
        b.x *= s; b.y *= s; b.z *= s; b.w *= s;
    }
    const float v[8] = {a.x, a.y, a.z, a.w, b.x, b.y, b.z, b.w};
    bf16x8 hv, lv;
#pragma unroll
    for (int j = 0; j < 8; ++j) {
        const bf16_t h = (bf16_t)v[j];
        hv[j] = h;
        lv[j] = (bf16_t)(v[j] - (float)h);
    }
    *reinterpret_cast<bf16x8*>(dH + (kg * 64 + r) * 8) = hv;
    *reinterpret_cast<bf16x8*>(dL + (kg * 64 + r) * 8) = lv;
}

__device__ __forceinline__ void loadB(const bf16_t* __restrict__ Wh, const bf16_t* __restrict__ Wl,
                                      int kc, int wn, int lane, bf16x8* Bh, bf16x8* Bl)
{
#pragma unroll
    for (int nt = 0; nt < 4; ++nt) {
        const size_t idx = (size_t)(((kc * 8) + wn * 4 + nt) * 64 + lane) * 8;
        Bh[nt] = *reinterpret_cast<const bf16x8*>(Wh + idx);
        Bl[nt] = *reinterpret_cast<const bf16x8*>(Wl + idx);
    }
}

// ---------------------------------------------------------------------------
// MFMA fused 2-layer MLP + LN, bf16x3 (split-fp32) precision. (same as R2)
// ---------------------------------------------------------------------------
template<int NSEG>
__global__ __launch_bounds__(256, 2)
void mfma_mlp_ln(const float* __restrict__ p0, const int* __restrict__ i0, const float* __restrict__ s0,
                 const float* __restrict__ p1, const int* __restrict__ i1, const float* __restrict__ s1,
                 const float* __restrict__ p2, const int* __restrict__ i2, const float* __restrict__ s2,
                 const float* __restrict__ p3, const int* __restrict__ i3, const float* __restrict__ s3,
                 const bf16_t* __restrict__ W1h, const bf16_t* __restrict__ W1l,
                 const bf16_t* __restrict__ W2h, const bf16_t* __restrict__ W2l,
                 const float* __restrict__ b1, const float* __restrict__ b2,
                 const float* __restrict__ gam, const float* __restrict__ bet,
                 float* __restrict__ outp)
{
    __shared__ bf16_t sA[2][2][4 * 64 * 8];
    __shared__ bf16_t sH[2][16 * 64 * 8];
    __shared__ float  redS[2][64], redQ[2][64];

    const int t = threadIdx.x;
    const int lane = t & 63;
    const int wv = t >> 6;
    const int wn = wv & 1, wm = wv >> 1;
    const int l15 = lane & 15, l4 = lane >> 4;
    const int row0 = blockIdx.x * 64;

    f32x4 acc[2][4];
#pragma unroll
    for (int mt = 0; mt < 2; ++mt)
#pragma unroll
        for (int nt = 0; nt < 4; ++nt) acc[mt][nt] = (f32x4)0.f;

    constexpr int NC1 = NSEG * 4;

    bf16x8 Bh[4], Bl[4], Bh2[4], Bl2[4];
    stage_chunk(p0,i0,s0, p1,i1,s1, p2,i2,s2, p3,i3,s3, 0, row0, t, sA[0][0], sA[0][1]);
    loadB(W1h, W1l, 0, wn, lane, Bh, Bl);

    int buf = 0;
#pragma unroll 1
    for (int kc = 0; kc < NC1; ++kc) {
        __syncthreads();
        const bool pre = (kc + 1 < NC1);
        if (pre) {
            stage_chunk(p0,i0,s0, p1,i1,s1, p2,i2,s2, p3,i3,s3, kc + 1, row0, t,
                        sA[buf ^ 1][0], sA[buf ^ 1][1]);
            loadB(W1h, W1l, kc + 1, wn, lane, Bh2, Bl2);
        }
        const bf16_t* baseH = sA[buf][0];
        const bf16_t* baseL = sA[buf][1];
#pragma unroll
        for (int mt = 0; mt < 2; ++mt) {
            const int ro = wm * 32 + mt * 16 + l15;
            const bf16x8 Ah = *reinterpret_cast<const bf16x8*>(baseH + (l4 * 64 + ro) * 8);
            const bf16x8 Al = *reinterpret_cast<const bf16x8*>(baseL + (l4 * 64 + ro) * 8);
#pragma unroll
            for (int nt = 0; nt < 4; ++nt) {
                acc[mt][nt] = mfma16(Al, Bh[nt], acc[mt][nt]);
                acc[mt][nt] = mfma16(Ah, Bl[nt], acc[mt][nt]);
                acc[mt][nt] = mfma16(Ah, Bh[nt], acc[mt][nt]);
            }
        }
        if (pre) {
#pragma unroll
            for (int q = 0; q < 4; ++q) { Bh[q] = Bh2[q]; Bl[q] = Bl2[q]; }
        }
        buf ^= 1;
    }

    // ---- transition: hidden = relu(acc + b1), split -> sH frag layout ----
#pragma unroll
    for (int mt = 0; mt < 2; ++mt)
#pragma unroll
        for (int nt = 0; nt < 4; ++nt) {
            const int col = wn * 64 + nt * 16 + l15;
            const float bb = b1[col];
#pragma unroll
            for (int r2 = 0; r2 < 4; ++r2) {
                const int rloc = wm * 32 + mt * 16 + l4 * 4 + r2;
                float v = acc[mt][nt][r2] + bb;
                v = v > 0.f ? v : 0.f;
                const bf16_t h = (bf16_t)v;
                const int sidx = (col >> 3) * 512 + rloc * 8 + (col & 7);
                sH[0][sidx] = h;
                sH[1][sidx] = (bf16_t)(v - (float)h);
                acc[mt][nt][r2] = 0.f;
            }
        }
    __syncthreads();

    // ---- phase 2: out = hidden @ W2 ----
    loadB(W2h, W2l, 0, wn, lane, Bh, Bl);
#pragma unroll 1
    for (int kc = 0; kc < 4; ++kc) {
        if (kc + 1 < 4) loadB(W2h, W2l, kc + 1, wn, lane, Bh2, Bl2);
#pragma unroll
        for (int mt = 0; mt < 2; ++mt) {
            const int ro = wm * 32 + mt * 16 + l15;
            const bf16x8 Ah = *reinterpret_cast<const bf16x8*>(sH[0] + ((kc * 4 + l4) * 64 + ro) * 8);
            const bf16x8 Al = *reinterpret_cast<const bf16x8*>(sH[1] + ((kc * 4 + l4) * 64 + ro) * 8);
#pragma unroll
            for (int nt = 0; nt < 4; ++nt) {
                acc[mt][nt] = mfma16(Al, Bh[nt], acc[mt][nt]);
                acc[mt][nt] = mfma16(Ah, Bl[nt], acc[mt][nt]);
                acc[mt][nt] = mfma16(Ah, Bh[nt], acc[mt][nt]);
            }
        }
        if (kc + 1 < 4) {
#pragma unroll
            for (int q = 0; q < 4; ++q) { Bh[q] = Bh2[q]; Bl[q] = Bl2[q]; }
        }
    }

    // ---- epilogue: bias2 + LayerNorm + affine ----
    float bb2[4], ggv[4], btv[4];
#pragma unroll
    for (int nt = 0; nt < 4; ++nt) {
        const int col = wn * 64 + nt * 16 + l15;
        bb2[nt] = b2[col]; ggv[nt] = gam[col]; btv[nt] = bet[col];
    }
#pragma unroll
    for (int mt = 0; mt < 2; ++mt)
#pragma unroll
        for (int r2 = 0; r2 < 4; ++r2) {
            float s = 0.f, q = 0.f;
#pragma unroll
            for (int nt = 0; nt < 4; ++nt) {
                const float v = acc[mt][nt][r2] + bb2[nt];
                s += v; q += v * v;
            }
            s += __shfl_xor(s, 1, 16); s += __shfl_xor(s, 2, 16);
            s += __shfl_xor(s, 4, 16); s += __shfl_xor(s, 8, 16);
            q += __shfl_xor(q, 1, 16); q += __shfl_xor(q, 2, 16);
            q += __shfl_xor(q, 4, 16); q += __shfl_xor(q, 8, 16);
            if (l15 == 0) {
                const int row = wm * 32 + mt * 16 + l4 * 4 + r2;
                redS[wn][row] = s; redQ[wn][row] = q;
            }
        }
    __syncthreads();
#pragma unroll
    for (int mt = 0; mt < 2; ++mt)
#pragma unroll
        for (int r2 = 0; r2 < 4; ++r2) {
            const int row = wm * 32 + mt * 16 + l4 * 4 + r2;
            const float S = redS[0][row] + redS[1][row];
            const float Q = redQ[0][row] + redQ[1][row];
            const float mean = S * (1.f / 128.f);
            const float var  = Q * (1.f / 128.f) - mean * mean;
            const float rstd = rsqrtf(var + 1e-5f);
            float* op = outp + (size_t)(row0 + row) * H;
#pragma unroll
            for (int nt = 0; nt < 4; ++nt) {
                const int col = wn * 64 + nt * 16 + l15;
                const float v = acc[mt][nt][r2] + bb2[nt];
                op[col] = (v - mean) * rstd * ggv[nt] + btv[nt];
            }
        }
}

// ---------------------------------------------------------------------------
// Input projection (fp32, same as R2)
// ---------------------------------------------------------------------------
template<int K>
__global__ __launch_bounds__(256, 2)
void proj_relu(const float* __restrict__ in, const float* __restrict__ W,
               const float* __restrict__ b, float* __restrict__ out)
{
    constexpr int LDAP = K + 4;
    __shared__ float sA[BM * LDAP];
    __shared__ float sWp[K * BN];

    const int tid = threadIdx.x;
    const int rg = tid >> 4, cg = tid & 15;
    const int m0 = rg * 4, n0 = cg * 8;
    const int row0 = blockIdx.x * BM;

    if constexpr (K == 64) {
        const int lr = tid >> 2, lc = (tid & 3) * 16;
        const float* srcp = in + (size_t)(row0 + lr) * K + lc;
#pragma unroll
        for (int q = 0; q < 16; q += 4) st4(&sA[lr * LDAP + lc + q], ld4(srcp + q));
        const int wrk = tid >> 2, wck = (tid & 3) * 32;
        const float* wsp = W + (size_t)wrk * BN + wck;
#pragma unroll
        for (int q = 0; q < 32; q += 4) st4(&sWp[wrk * BN + wck + q], ld4(wsp + q));
    } else {
        const int lr = tid >> 2, lc = (tid & 3) * 8;
        const float* srcp = in + (size_t)(row0 + lr) * K + lc;
        st4(&sA[lr * LDAP + lc],     ld4(srcp));
        st4(&sA[lr * LDAP + lc + 4], ld4(srcp + 4));
        const int wrk = tid >> 3, wck = (tid & 7) * 16;
        const float* wsp = W + (size_t)wrk * BN + wck;
#pragma unroll
        for (int q = 0; q < 16; q += 4) st4(&sWp[wrk * BN + wck + q], ld4(wsp + q));
    }
    __syncthreads();

    float acc[4][8];
#pragma unroll
    for (int i = 0; i < 4; ++i)
#pragma unroll
        for (int j = 0; j < 8; ++j) acc[i][j] = 0.f;

#pragma unroll 8
    for (int k = 0; k < K; ++k) {
        float a[4];
#pragma unroll
        for (int i = 0; i < 4; ++i) a[i] = sA[(m0 + i) * LDAP + k];
        const float4 wA = ld4(&sWp[k * BN + n0]);
        const float4 wB = ld4(&sWp[k * BN + n0 + 4]);
        const float w[8] = {wA.x, wA.y, wA.z, wA.w, wB.x, wB.y, wB.z, wB.w};
#pragma unroll
        for (int i = 0; i < 4; ++i)
#pragma unroll
            for (int j = 0; j < 8; ++j)
                acc[i][j] = fmaf(a[i], w[j], acc[i][j]);
    }

    const float4 bA = ld4(&b[n0]), bB = ld4(&b[n0 + 4]);
    const float bb[8] = {bA.x, bA.y, bA.z, bA.w, bB.x, bB.y, bB.z, bB.w};
#pragma unroll
    for (int i = 0; i < 4; ++i) {
        float o[8];
#pragma unroll
        for (int j = 0; j < 8; ++j) {
            const float v = acc[i][j] + bb[j];
            o[j] = v > 0.f ? v : 0.f;
        }
        float* op = out + (size_t)(row0 + m0 + i) * H + n0;
        st4(op,     make_float4(o[0], o[1], o[2], o[3]));
        st4(op + 4, make_float4(o[4], o[5], o[6], o[7]));
    }
}

// ---------------------------------------------------------------------------
// Head (fp32, same as R2)
// ---------------------------------------------------------------------------
__global__ __launch_bounds__(256, 2)
void head_mlp(const float* __restrict__ in, const float* __restrict__ W1,
              const float* __restrict__ b1, const float* __restrict__ w2,
              const float* __restrict__ b2, float* __restrict__ outp)
{
    __shared__ float sA[BM * LDA];
    __shared__ float sW[BK * BN];

    const int tid = threadIdx.x;
    const int rg = tid >> 4, cg = tid & 15;
    const int m0 = rg * 4, n0 = cg * 8;
    const int row0 = blockIdx.x * BM;
    const int lr = tid >> 2, lc = (tid & 3) * 8;
    const int wr = tid >> 3, wc = (tid & 7) * 16;

    float acc[4][8];
#pragma unroll
    for (int i = 0; i < 4; ++i)
#pragma unroll
        for (int j = 0; j < 8; ++j) acc[i][j] = 0.f;

#pragma unroll 1
    for (int kc = 0; kc < 4; ++kc) {
        const int koff = kc * 32;
        const float* srcp = in + (size_t)(row0 + lr) * H + koff + lc;
        st4(&sA[lr * LDA + lc],     ld4(srcp));
        st4(&sA[lr * LDA + lc + 4], ld4(srcp + 4));
        const float* wsrc = W1 + (size_t)koff * BN + wr * BN + wc;
        st4(&sW[wr * BN + wc],      ld4(wsrc));
        st4(&sW[wr * BN + wc + 4],  ld4(wsrc + 4));
        st4(&sW[wr * BN + wc + 8],  ld4(wsrc + 8));
        st4(&sW[wr * BN + wc + 12], ld4(wsrc + 12));
        __syncthreads();
#pragma unroll
        for (int kk = 0; kk < BK; ++kk) {
            float a[4];
#pragma unroll
            for (int i = 0; i < 4; ++i) a[i] = sA[(m0 + i) * LDA + kk];
            const float4 wA = ld4(&sW[kk * BN + n0]);
            const float4 wB = ld4(&sW[kk * BN + n0 + 4]);
            const float w[8] = {wA.x, wA.y, wA.z, wA.w, wB.x, wB.y, wB.z, wB.w};
#pragma unroll
            for (int i = 0; i < 4; ++i)
#pragma unroll
                for (int j = 0; j < 8; ++j)
                    acc[i][j] = fmaf(a[i], w[j], acc[i][j]);
        }
        __syncthreads();
    }

    const float4 bA = ld4(&b1[n0]),  bB = ld4(&b1[n0 + 4]);
    const float4 vA = ld4(&w2[n0]),  vB = ld4(&w2[n0 + 4]);
    const float bb[8] = {bA.x, bA.y, bA.z, bA.w, bB.x, bB.y, bB.z, bB.w};
    const float vv[8] = {vA.x, vA.y, vA.z, vA.w, vB.x, vB.y, vB.z, vB.w};
#pragma unroll
    for (int i = 0; i < 4; ++i) {
        float p = 0.f;
#pragma unroll
        for (int j = 0; j < 8; ++j) {
            float h = acc[i][j] + bb[j];
            h = h > 0.f ? h : 0.f;
            p = fmaf(h, vv[j], p);
        }
        p += __shfl_xor(p, 1, 16); p += __shfl_xor(p, 2, 16);
        p += __shfl_xor(p, 4, 16); p += __shfl_xor(p, 8, 16);
        if (cg == 0) outp[row0 + m0 + i] = p + b2[0];
    }
}

// ---------------------------------------------------------------------------
// CSR build (once per launch; edge_index is fixed)
// ---------------------------------------------------------------------------
__global__ void count_int_k(const int* __restrict__ dst, int* __restrict__ cnt)
{
    const int i = blockIdx.x * 256 + threadIdx.x;
    atomicAdd(&cnt[dst[i]], 1);
}

// per-graph exclusive scan: all edges of graph g land in node range [g*512,(g+1)*512)
// and occupy CSR slots [g*4096, (g+1)*4096).
__global__ void scan_graph_k(const int* __restrict__ cnt, int* __restrict__ off)
{
    __shared__ int s[256];
    const int g = blockIdx.x;
    const int t = threadIdx.x;       // 256 threads, 2 elements each
    const int a = cnt[g * Pn + 2 * t];
    const int b = cnt[g * Pn + 2 * t + 1];
    s[t] = a + b;
    __syncthreads();
    for (int d = 1; d < 256; d <<= 1) {
        const int v = (t >= d) ? s[t - d] : 0;
        __syncthreads();
        s[t] += v;
        __syncthreads();
    }
    const int excl = s[t] - (a + b);
    off[g * Pn + 2 * t]     = g * EPGn + excl;
    off[g * Pn + 2 * t + 1] = g * EPGn + excl + a;
}

__global__ void place_k(const int* __restrict__ dst, const int* __restrict__ off,
                        int* __restrict__ cur, int* __restrict__ perm)
{
    const int i = blockIdx.x * 256 + threadIdx.x;
    const int d = dst[i];
    const int p = off[d] + atomicAdd(&cur[d], 1);
    perm[p] = i;
}

// deterministic order: insertion-sort each node's bucket by edge id (~8 elems)
__global__ void sort_bucket_k(int* __restrict__ perm, const int* __restrict__ off,
                              const int* __restrict__ cnt)
{
    const int n = blockIdx.x * 256 + threadIdx.x;
    if (n >= Nn) return;
    const int o = off[n], c = cnt[n];
    for (int i = 1; i < c; ++i) {
        const int key = perm[o + i];
        int j = i - 1;
        while (j >= 0 && perm[o + j] > key) { perm[o + j + 1] = perm[o + j]; --j; }
        perm[o + j + 1] = key;
    }
}

// agg[n] = mean over incoming edges of e[eid]; 32 lanes per node, 4 cols/lane
__global__ __launch_bounds__(256)
void gather_agg_k(const float* __restrict__ he, const int* __restrict__ perm,
                  const int* __restrict__ off, const int* __restrict__ cnt,
                  float* __restrict__ agg)
{
    const int tid = threadIdx.x;
    const int n = blockIdx.x * 8 + (tid >> 5);
    const int c0 = (tid & 31) * 4;
    const int o = off[n], c = cnt[n];
    float ax = 0.f, ay = 0.f, az = 0.f, aw = 0.f;
    for (int k = 0; k < c; ++k) {
        const int eid = perm[o + k];
        const float4 v = ld4(&he[(size_t)eid * H + c0]);
        ax += v.x; ay += v.y; az += v.z; aw += v.w;
    }
    const float inv = 1.f / fmaxf((float)c, 1.f);
    st4(&agg[(size_t)n * H + c0], make_float4(ax * inv, ay * inv, az * inv, aw * inv));
}

// ---------------------------------------------------------------------------
// small utility kernels
// ---------------------------------------------------------------------------
__global__ void init_u_k(float* __restrict__ u, const float* __restrict__ u0)
{
    const int idx = blockIdx.x * 256 + threadIdx.x;
    u[idx] = u0[idx & (H - 1)];
}

__global__ void make_ebatch_k(const int* __restrict__ src, const int* __restrict__ batch,
                              int* __restrict__ eb)
{
    const int i = blockIdx.x * 256 + threadIdx.x;
    eb[i] = batch[src[i]];
}

__global__ void pool_mean_k(const float* __restrict__ in, float* __restrict__ out,
                            int rpg, int splits, float scale)
{
    const int g  = blockIdx.x / splits;
    const int sp = blockIdx.x % splits;
    const int rpb = rpg / splits;
    const int tid = threadIdx.x;
    const int col = tid & (H - 1);
    const int half = tid >> 7;
    const size_t base = ((size_t)g * rpg + (size_t)sp * rpb) * H;
    float s = 0.f;
    const int r0 = half * (rpb / 2), r1 = r0 + rpb / 2;
    for (int r = r0; r < r1; ++r) s += in[base + (size_t)r * H + col];
    __shared__ float red[256];
    red[tid] = s;
    __syncthreads();
    if (half == 0) atomicAdd(&out[g * H + col], (red[col] + red[128 + col]) * scale);
}

__global__ void softmax_head_k(const float* __restrict__ logits, float* __restrict__ outp)
{
    const int g = blockIdx.x;
    const int tid = threadIdx.x;
    const float* lg = logits + (size_t)g * Pn;
    const float v0 = lg[tid], v1 = lg[tid + 256];
    float bv; int bi;
    if (v1 > v0) { bv = v1; bi = tid + 256; } else { bv = v0; bi = tid; }

    __shared__ float sv[256];
    __shared__ int   si[256];
    sv[tid] = bv; si[tid] = bi;
    __syncthreads();
    for (int s = 128; s > 0; s >>= 1) {
        if (tid < s) {
            const float ov = sv[tid + s]; const int oi = si[tid + s];
            if (ov > sv[tid] || (ov == sv[tid] && oi < si[tid])) { sv[tid] = ov; si[tid] = oi; }
        }
        __syncthreads();
    }
    const float mx = sv[0];
    const int ai = si[0];
    __syncthreads();

    const float d0 = v0 - mx, d1 = v1 - mx;
    const float e0 = __expf(d0), e1 = __expf(d1);
    __shared__ float ss[256];
    __shared__ float st[256];
    ss[tid] = e0 + e1;
    st[tid] = e0 * d0 + e1 * d1;
    __syncthreads();
    for (int s = 128; s > 0; s >>= 1) {
        if (tid < s) { ss[tid] += ss[tid + s]; st[tid] += st[tid + s]; }
        __syncthreads();
    }
    if (tid == 0) {
        const float S = ss[0];
        const float logS = logf(S);
        outp[g]            = (float)ai;
        outp[Gn + g]       = -logS;
        outp[2 * Gn + g]   = logS - st[0] / S;
    }
}

} // namespace

extern "C" void kernel_launch(void* const* d_in, const int* in_sizes, int n_in,
                              void* d_out, int out_size, void* d_ws, size_t ws_size,
                              hipStream_t stream)
{
    (void)in_sizes; (void)n_in; (void)out_size; (void)ws_size;

    const float* x     = (const float*)d_in[0];
    const float* ea    = (const float*)d_in[1];
    const int*   ei    = (const int*)d_in[2];
    const int*   batch = (const int*)d_in[3];
    const float* Wn  = (const float*)d_in[6];
    const float* bn_ = (const float*)d_in[7];
    const float* We  = (const float*)d_in[8];
    const float* be_ = (const float*)d_in[9];
    const float* u0  = (const float*)d_in[10];
    const float* eW1 = (const float*)d_in[11];
    const float* eb1 = (const float*)d_in[12];
    const float* eW2 = (const float*)d_in[13];
    const float* eb2 = (const float*)d_in[14];
    const float* eg  = (const float*)d_in[15];
    const float* ebn = (const float*)d_in[16];
    const float* nW1 = (const float*)d_in[17];
    const float* nb1 = (const float*)d_in[18];
    const float* nW2 = (const float*)d_in[19];
    const float* nb2 = (const float*)d_in[20];
    const float* ng  = (const float*)d_in[21];
    const float* nbn = (const float*)d_in[22];
    const float* gW1 = (const float*)d_in[23];
    const float* gb1 = (const float*)d_in[24];
    const float* gW2 = (const float*)d_in[25];
    const float* gb2 = (const float*)d_in[26];
    const float* gg  = (const float*)d_in[27];
    const float* gbn = (const float*)d_in[28];
    const float* aW1 = (const float*)d_in[29];
    const float* ab1 = (const float*)d_in[30];
    const float* aW2 = (const float*)d_in[31];
    const float* ab2 = (const float*)d_in[32];
    const float* cW1 = (const float*)d_in[33];
    const float* cb1 = (const float*)d_in[34];
    const float* cW2 = (const float*)d_in[35];
    const float* cb2 = (const float*)d_in[36];

    const int* srcI = ei;
    const int* dstI = ei + En;

    float* ws     = (float*)d_ws;
    float* hx     = ws;                              // N*128
    float* he     = hx + (size_t)Nn * H;             // E*128
    float* agg    = he + (size_t)En * H;             // N*128
    float* u      = agg + (size_t)Nn * H;            // 64*128
    float* nmean  = u + Gn * H;
    float* emean  = nmean + Gn * H;
    float* logits = emean + Gn * H;                  // N
    int*   ebatch = (int*)(logits + Nn);             // E
    int*   cnt    = ebatch + En;                     // N
    int*   off    = cnt + Nn;                        // N
    int*   cur    = off + Nn;                        // N
    int*   perm   = cur + Nn;                        // E
    bf16_t* frag  = (bf16_t*)(perm + En);
    bf16_t* eW1h = frag;              bf16_t* eW1l = eW1h + 512 * 128;   frag += 2 * 512 * 128;
    bf16_t* eW2h = frag;              bf16_t* eW2l = eW2h + 128 * 128;   frag += 2 * 128 * 128;
    bf16_t* nW1h = frag;              bf16_t* nW1l = nW1h + 384 * 128;   frag += 2 * 384 * 128;
    bf16_t* nW2h = frag;              bf16_t* nW2l = nW2h + 128 * 128;   frag += 2 * 128 * 128;
    bf16_t* gW1h = frag;              bf16_t* gW1l = gW1h + 384 * 128;   frag += 2 * 384 * 128;
    bf16_t* gW2h = frag;              bf16_t* gW2l = gW2h + 128 * 128;

    float* outp = (float*)d_out;

    // weight prep
    prep_wfrag<<<(512 * 128) / 256, 256, 0, stream>>>(eW1, eW1h, eW1l);
    prep_wfrag<<<(128 * 128) / 256, 256, 0, stream>>>(eW2, eW2h, eW2l);
    prep_wfrag<<<(384 * 128) / 256, 256, 0, stream>>>(nW1, nW1h, nW1l);
    prep_wfrag<<<(128 * 128) / 256, 256, 0, stream>>>(nW2, nW2h, nW2l);
    prep_wfrag<<<(384 * 128) / 256, 256, 0, stream>>>(gW1, gW1h, gW1l);
    prep_wfrag<<<(128 * 128) / 256, 256, 0, stream>>>(gW2, gW2h, gW2l);

    // CSR build (dst is constant across layers)
    hipMemsetAsync(cnt, 0, Nn * sizeof(int), stream);
    hipMemsetAsync(cur, 0, Nn * sizeof(int), stream);
    count_int_k<<<En / 256, 256, 0, stream>>>(dstI, cnt);
    scan_graph_k<<<Gn, 256, 0, stream>>>(cnt, off);
    place_k<<<En / 256, 256, 0, stream>>>(dstI, off, cur, perm);
    sort_bucket_k<<<(Nn + 255) / 256, 256, 0, stream>>>(perm, off, cnt);

    // input projections + constants
    proj_relu<64><<<Nn / BM, 256, 0, stream>>>(x, Wn, bn_, hx);
    proj_relu<32><<<En / BM, 256, 0, stream>>>(ea, We, be_, he);
    init_u_k<<<(Gn * H) / 256, 256, 0, stream>>>(u, u0);
    make_ebatch_k<<<En / 256, 256, 0, stream>>>(srcI, batch, ebatch);

    for (int l = 0; l < 2; ++l) {
        // edge update (in-place on he)
        mfma_mlp_ln<4><<<En / 64, 256, 0, stream>>>(
            hx, srcI, nullptr,
            hx, dstI, nullptr,
            he, nullptr, nullptr,
            u,  ebatch, nullptr,
            eW1h, eW1l, eW2h, eW2l, eb1, eb2, eg, ebn, he);
        // agg = mean of incoming edge messages (CSR gather, deterministic)
        gather_agg_k<<<Nn / 8, 256, 0, stream>>>(he, perm, off, cnt, agg);
        // node update (in-place on hx)
        mfma_mlp_ln<3><<<Nn / 64, 256, 0, stream>>>(
            hx, nullptr, nullptr,
            agg, nullptr, nullptr,
            u,  batch, nullptr,
            nullptr, nullptr, nullptr,
            nW1h, nW1l, nW2h, nW2l, nb1, nb2, ng, nbn, hx);
        // global update (in-place on u)
        hipMemsetAsync(nmean, 0, Gn * H * sizeof(float), stream);
        hipMemsetAsync(emean, 0, Gn * H * sizeof(float), stream);
        pool_mean_k<<<Gn * 4, 256, 0, stream>>>(hx, nmean, Pn, 4, 1.f / Pn);
        pool_mean_k<<<Gn * 16, 256, 0, stream>>>(he, emean, EPGn, 16, 1.f / EPGn);
        mfma_mlp_ln<3><<<1, 256, 0, stream>>>(
            u, nullptr, nullptr,
            nmean, nullptr, nullptr,
            emean, nullptr, nullptr,
            nullptr, nullptr, nullptr,
            gW1h, gW1l, gW2h, gW2l, gb1, gb2, gg, gbn, u);
    }

    head_mlp<<<Nn / BM, 256, 0, stream>>>(hx, aW1, ab1, aW2, ab2, logits);
    softmax_head_k<<<Gn, 256, 0, stream>>>(logits, outp);
    head_mlp<<<1, 256, 0, stream>>>(u, cW1, cb1, cW2, cb2, outp + 3 * Gn);
}

// Round 4
// 627.340 us; speedup vs baseline: 4.1909x; 1.2139x over previous
//
#include <hip/hip_runtime.h>
#include <cstddef>

namespace {

constexpr int Gn  = 64;
constexpr int Pn  = 512;
constexpr int EPGn= 4096;
constexpr int Nn  = Gn * Pn;    // 32768 nodes
constexpr int En  = Gn * EPGn;  // 262144 edges
constexpr int H   = 128;

constexpr int BM = 64, BK = 32, BN = 128;
constexpr int LDA = BK + 4;

typedef __bf16 bf16_t;
typedef bf16_t bf16x8 __attribute__((ext_vector_type(8)));
typedef float  f32x4  __attribute__((ext_vector_type(4)));

__device__ __forceinline__ float4 ld4(const float* p) { return *reinterpret_cast<const float4*>(p); }
__device__ __forceinline__ void st4(float* p, const float4 v) { *reinterpret_cast<float4*>(p) = v; }
__device__ __forceinline__ f32x4 mfma16(bf16x8 a, bf16x8 b, f32x4 c) {
    return __builtin_amdgcn_mfma_f32_16x16x32_bf16(a, b, c, 0, 0, 0);
}

// ---------------------------------------------------------------------------
// Weight prep: fp32 W[K][128] -> bf16 hi/lo in MFMA B-fragment-major layout.
// ---------------------------------------------------------------------------
__global__ void prep_wfrag(const float* __restrict__ W, bf16_t* __restrict__ Bh,
                           bf16_t* __restrict__ Bl)
{
    const int i = blockIdx.x * 256 + threadIdx.x;   // i < K*128
    const int k = i >> 7, n = i & 127;
    const float v = W[i];
    const bf16_t h = (bf16_t)v;
    const bf16_t l = (bf16_t)(v - (float)h);
    const int idx = ((((k >> 5) * 8) + (n >> 4)) * 64 + ((k >> 3) & 3) * 16 + (n & 15)) * 8 + (k & 7);
    Bh[idx] = h; Bl[idx] = l;
}

__device__ __forceinline__ void split8(const float4 a, const float4 b, bf16x8& h, bf16x8& l)
{
    const float v[8] = {a.x, a.y, a.z, a.w, b.x, b.y, b.z, b.w};
#pragma unroll
    for (int j = 0; j < 8; ++j) {
        const bf16_t hh = (bf16_t)v[j];
        h[j] = hh;
        l[j] = (bf16_t)(v[j] - (float)hh);
    }
}

__device__ __forceinline__ void loadB(const bf16_t* __restrict__ Wh, const bf16_t* __restrict__ Wl,
                                      int kc32, int wn, int lane, bf16x8* Bh, bf16x8* Bl)
{
#pragma unroll
    for (int nt = 0; nt < 4; ++nt) {
        const size_t idx = (size_t)(((kc32 * 8) + wn * 4 + nt) * 64 + lane) * 8;
        Bh[nt] = *reinterpret_cast<const bf16x8*>(Wh + idx);
        Bl[nt] = *reinterpret_cast<const bf16x8*>(Wl + idx);
    }
}

__device__ __forceinline__ void seg_sel(int seg,
    const float* p0, const float* p1, const float* p2, const float* p3,
    int s0, int s1, int s2, int s3, const float*& p, int& srow)
{
    if (seg == 0)      { p = p0; srow = s0; }
    else if (seg == 1) { p = p1; srow = s1; }
    else if (seg == 2) { p = p2; srow = s2; }
    else               { p = p3; srow = s3; }
}

// ---------------------------------------------------------------------------
// MFMA fused 2-layer MLP + LN, bf16x3 (split-fp32) precision.
// Block: 256 thr = 4 waves (2 wm x 2 wn); 64 rows x 128 cols.
// Phase 1: K = NSEG*128 in 64-wide chunks, double-buffered LDS overlay.
// Phase 2: hidden (64x128) relu'd/split into the SAME LDS (overlay), @ W2, LN.
// Optional fused per-graph column-mean pool (atomicAdd into pool).
// LDS: 32 KB union + 1 KB reductions -> 4 blocks/CU.
// ---------------------------------------------------------------------------
template<int NSEG>
__global__ __launch_bounds__(256, 4)
void mfma_mlp_ln(const float* __restrict__ p0, const int* __restrict__ i0,
                 const float* __restrict__ p1, const int* __restrict__ i1,
                 const float* __restrict__ p2, const int* __restrict__ i2,
                 const float* __restrict__ p3, const int* __restrict__ i3,
                 const bf16_t* __restrict__ W1h, const bf16_t* __restrict__ W1l,
                 const bf16_t* __restrict__ W2h, const bf16_t* __restrict__ W2l,
                 const float* __restrict__ b1, const float* __restrict__ b2,
                 const float* __restrict__ gam, const float* __restrict__ bet,
                 float* __restrict__ outp,
                 float* __restrict__ pool, int gshift, float pscale)
{
    // Overlay: phase1 A-tiles (2 bufs x [hi 8KB | lo 8KB]) alias phase2 hidden
    // ([hi 16KB | lo 16KB]). Never live at the same time (barriers between).
    __shared__ __align__(16) char smem[32 * 1024];
    __shared__ float redS[2][64], redQ[2][64];

    const int t = threadIdx.x;
    const int lane = t & 63;
    const int wv = t >> 6;
    const int wn = wv & 1, wm = wv >> 1;
    const int l15 = lane & 15, l4 = lane >> 4;
    const int row0 = blockIdx.x * 64;

    const int r  = t & 63;     // staging row
    const int kg = t >> 6;     // staging k-group (0..3)

    // hoist gather indices out of the K-loop (kills dependent-load chain)
    const int s0 = i0 ? i0[row0 + r] : row0 + r;
    const int s1 = (NSEG > 1) ? (i1 ? i1[row0 + r] : row0 + r) : 0;
    const int s2 = (NSEG > 2) ? (i2 ? i2[row0 + r] : row0 + r) : 0;
    const int s3 = (NSEG > 3) ? (i3 ? i3[row0 + r] : row0 + r) : 0;

    f32x4 acc[2][4];
#pragma unroll
    for (int mt = 0; mt < 2; ++mt)
#pragma unroll
        for (int nt = 0; nt < 4; ++nt) acc[mt][nt] = (f32x4)0.f;

    constexpr int NC = NSEG * 2;   // 64-K chunks

    // ---- initial stage: chunk 0 (seg 0, k-half 0) -> buf 0 ----
    {
        const float* sp = p0 + (size_t)s0 * H + kg * 8;
        const float4 a0 = ld4(sp),      b0 = ld4(sp + 4);
        const float4 a1 = ld4(sp + 32), b1v = ld4(sp + 36);
        bf16_t* dH = (bf16_t*)smem;
        bf16_t* dL = dH + 4096;
        bf16x8 h, l;
        split8(a0, b0, h, l);
        *reinterpret_cast<bf16x8*>(dH + ((kg)     * 64 + r) * 8) = h;
        *reinterpret_cast<bf16x8*>(dL + ((kg)     * 64 + r) * 8) = l;
        split8(a1, b1v, h, l);
        *reinterpret_cast<bf16x8*>(dH + ((kg + 4) * 64 + r) * 8) = h;
        *reinterpret_cast<bf16x8*>(dL + ((kg + 4) * 64 + r) * 8) = l;
    }

    // ---- phase 1: hidden = A @ W1 ----
#pragma unroll 1
    for (int kc = 0; kc < NC; ++kc) {
        __syncthreads();
        const bool pre = (kc + 1 < NC);
        float4 a0, b0, a1, b1v;
        if (pre) {   // issue next-chunk loads EARLY (complete after MFMA below)
            const int seg = (kc + 1) >> 1, kh = (kc + 1) & 1;
            const float* p; int srow;
            seg_sel(seg, p0, p1, p2, p3, s0, s1, s2, s3, p, srow);
            const float* sp = p + (size_t)srow * H + kh * 64 + kg * 8;
            a0 = ld4(sp);      b0  = ld4(sp + 4);
            a1 = ld4(sp + 32); b1v = ld4(sp + 36);
        }

        const bf16_t* aH = (const bf16_t*)(smem + (size_t)(kc & 1) * 16384);
        const bf16_t* aL = aH + 4096;
#pragma unroll
        for (int ks = 0; ks < 2; ++ks) {
            bf16x8 Bh[4], Bl[4];
            loadB(W1h, W1l, kc * 2 + ks, wn, lane, Bh, Bl);
#pragma unroll
            for (int mt = 0; mt < 2; ++mt) {
                const int ro = wm * 32 + mt * 16 + l15;
                const bf16x8 Ah = *reinterpret_cast<const bf16x8*>(aH + ((ks * 4 + l4) * 64 + ro) * 8);
                const bf16x8 Al = *reinterpret_cast<const bf16x8*>(aL + ((ks * 4 + l4) * 64 + ro) * 8);
#pragma unroll
                for (int nt = 0; nt < 4; ++nt) {
                    acc[mt][nt] = mfma16(Al, Bh[nt], acc[mt][nt]);
                    acc[mt][nt] = mfma16(Ah, Bl[nt], acc[mt][nt]);
                    acc[mt][nt] = mfma16(Ah, Bh[nt], acc[mt][nt]);
                }
            }
        }

        if (pre) {   // write-late half of the async stage (T14)
            bf16_t* dH = (bf16_t*)(smem + (size_t)((kc & 1) ^ 1) * 16384);
            bf16_t* dL = dH + 4096;
            bf16x8 h, l;
            split8(a0, b0, h, l);
            *reinterpret_cast<bf16x8*>(dH + ((kg)     * 64 + r) * 8) = h;
            *reinterpret_cast<bf16x8*>(dL + ((kg)     * 64 + r) * 8) = l;
            split8(a1, b1v, h, l);
            *reinterpret_cast<bf16x8*>(dH + ((kg + 4) * 64 + r) * 8) = h;
            *reinterpret_cast<bf16x8*>(dL + ((kg + 4) * 64 + r) * 8) = l;
        }
    }

    __syncthreads();   // all sA reads done before hidden overlays it

    // ---- transition: hidden = relu(acc + b1), split -> LDS frag layout ----
    {
        bf16_t* sHh = (bf16_t*)smem;
        bf16_t* sHl = sHh + 8192;
#pragma unroll
        for (int mt = 0; mt < 2; ++mt)
#pragma unroll
            for (int nt = 0; nt < 4; ++nt) {
                const int col = wn * 64 + nt * 16 + l15;
                const float bb = b1[col];
#pragma unroll
                for (int r2 = 0; r2 < 4; ++r2) {
                    const int rloc = wm * 32 + mt * 16 + l4 * 4 + r2;
                    float v = acc[mt][nt][r2] + bb;
                    v = v > 0.f ? v : 0.f;
                    const bf16_t h = (bf16_t)v;
                    const int sidx = (col >> 3) * 512 + rloc * 8 + (col & 7);
                    sHh[sidx] = h;
                    sHl[sidx] = (bf16_t)(v - (float)h);
                    acc[mt][nt][r2] = 0.f;
                }
            }
    }
    __syncthreads();

    // ---- phase 2: out = hidden @ W2 ----
    {
        const bf16_t* sHh = (const bf16_t*)smem;
        const bf16_t* sHl = sHh + 8192;
#pragma unroll 1
        for (int kc2 = 0; kc2 < 4; ++kc2) {
            bf16x8 Bh[4], Bl[4];
            loadB(W2h, W2l, kc2, wn, lane, Bh, Bl);
#pragma unroll
            for (int mt = 0; mt < 2; ++mt) {
                const int ro = wm * 32 + mt * 16 + l15;
                const bf16x8 Ah = *reinterpret_cast<const bf16x8*>(sHh + ((kc2 * 4 + l4) * 64 + ro) * 8);
                const bf16x8 Al = *reinterpret_cast<const bf16x8*>(sHl + ((kc2 * 4 + l4) * 64 + ro) * 8);
#pragma unroll
                for (int nt = 0; nt < 4; ++nt) {
                    acc[mt][nt] = mfma16(Al, Bh[nt], acc[mt][nt]);
                    acc[mt][nt] = mfma16(Ah, Bl[nt], acc[mt][nt]);
                    acc[mt][nt] = mfma16(Ah, Bh[nt], acc[mt][nt]);
                }
            }
        }
    }

    // ---- epilogue: bias2 + LayerNorm + affine (+ fused per-graph pool) ----
    float bb2[4], ggv[4], btv[4];
#pragma unroll
    for (int nt = 0; nt < 4; ++nt) {
        const int col = wn * 64 + nt * 16 + l15;
        bb2[nt] = b2[col]; ggv[nt] = gam[col]; btv[nt] = bet[col];
    }
#pragma unroll
    for (int mt = 0; mt < 2; ++mt)
#pragma unroll
        for (int r2 = 0; r2 < 4; ++r2) {
            float s = 0.f, q = 0.f;
#pragma unroll
            for (int nt = 0; nt < 4; ++nt) {
                const float v = acc[mt][nt][r2] + bb2[nt];
                s += v; q += v * v;
            }
            s += __shfl_xor(s, 1, 16); s += __shfl_xor(s, 2, 16);
            s += __shfl_xor(s, 4, 16); s += __shfl_xor(s, 8, 16);
            q += __shfl_xor(q, 1, 16); q += __shfl_xor(q, 2, 16);
            q += __shfl_xor(q, 4, 16); q += __shfl_xor(q, 8, 16);
            if (l15 == 0) {
                const int row = wm * 32 + mt * 16 + l4 * 4 + r2;
                redS[wn][row] = s; redQ[wn][row] = q;
            }
        }
    __syncthreads();

    float cs[4] = {0.f, 0.f, 0.f, 0.f};
#pragma unroll
    for (int mt = 0; mt < 2; ++mt)
#pragma unroll
        for (int r2 = 0; r2 < 4; ++r2) {
            const int row = wm * 32 + mt * 16 + l4 * 4 + r2;
            const float S = redS[0][row] + redS[1][row];
            const float Q = redQ[0][row] + redQ[1][row];
            const float mean = S * (1.f / 128.f);
            const float var  = Q * (1.f / 128.f) - mean * mean;
            const float rstd = rsqrtf(var + 1e-5f);
            float* op = outp + (size_t)(row0 + row) * H;
#pragma unroll
            for (int nt = 0; nt < 4; ++nt) {
                const int col = wn * 64 + nt * 16 + l15;
                const float v = acc[mt][nt][r2] + bb2[nt];
                const float o = (v - mean) * rstd * ggv[nt] + btv[nt];
                op[col] = o;
                cs[nt] += o;
            }
        }

    if (pool != nullptr) {
        const int g = row0 >> gshift;   // block's rows lie in one graph
#pragma unroll
        for (int nt = 0; nt < 4; ++nt) {
            float s = cs[nt];
            s += __shfl_xor(s, 16);
            s += __shfl_xor(s, 32);
            if (l4 == 0)
                atomicAdd(&pool[(size_t)g * H + wn * 64 + nt * 16 + l15], s * pscale);
        }
    }
}

// ---------------------------------------------------------------------------
// Input projection (fp32)
// ---------------------------------------------------------------------------
template<int K>
__global__ __launch_bounds__(256, 2)
void proj_relu(const float* __restrict__ in, const float* __restrict__ W,
               const float* __restrict__ b, float* __restrict__ out)
{
    constexpr int LDAP = K + 4;
    __shared__ float sA[BM * LDAP];
    __shared__ float sWp[K * BN];

    const int tid = threadIdx.x;
    const int rg = tid >> 4, cg = tid & 15;
    const int m0 = rg * 4, n0 = cg * 8;
    const int row0 = blockIdx.x * BM;

    if constexpr (K == 64) {
        const int lr = tid >> 2, lc = (tid & 3) * 16;
        const float* srcp = in + (size_t)(row0 + lr) * K + lc;
#pragma unroll
        for (int q = 0; q < 16; q += 4) st4(&sA[lr * LDAP + lc + q], ld4(srcp + q));
        const int wrk = tid >> 2, wck = (tid & 3) * 32;
        const float* wsp = W + (size_t)wrk * BN + wck;
#pragma unroll
        for (int q = 0; q < 32; q += 4) st4(&sWp[wrk * BN + wck + q], ld4(wsp + q));
    } else {
        const int lr = tid >> 2, lc = (tid & 3) * 8;
        const float* srcp = in + (size_t)(row0 + lr) * K + lc;
        st4(&sA[lr * LDAP + lc],     ld4(srcp));
        st4(&sA[lr * LDAP + lc + 4], ld4(srcp + 4));
        const int wrk = tid >> 3, wck = (tid & 7) * 16;
        const float* wsp = W + (size_t)wrk * BN + wck;
#pragma unroll
        for (int q = 0; q < 16; q += 4) st4(&sWp[wrk * BN + wck + q], ld4(wsp + q));
    }
    __syncthreads();

    float acc[4][8];
#pragma unroll
    for (int i = 0; i < 4; ++i)
#pragma unroll
        for (int j = 0; j < 8; ++j) acc[i][j] = 0.f;

#pragma unroll 8
    for (int k = 0; k < K; ++k) {
        float a[4];
#pragma unroll
        for (int i = 0; i < 4; ++i) a[i] = sA[(m0 + i) * LDAP + k];
        const float4 wA = ld4(&sWp[k * BN + n0]);
        const float4 wB = ld4(&sWp[k * BN + n0 + 4]);
        const float w[8] = {wA.x, wA.y, wA.z, wA.w, wB.x, wB.y, wB.z, wB.w};
#pragma unroll
        for (int i = 0; i < 4; ++i)
#pragma unroll
            for (int j = 0; j < 8; ++j)
                acc[i][j] = fmaf(a[i], w[j], acc[i][j]);
    }

    const float4 bA = ld4(&b[n0]), bB = ld4(&b[n0 + 4]);
    const float bb[8] = {bA.x, bA.y, bA.z, bA.w, bB.x, bB.y, bB.z, bB.w};
#pragma unroll
    for (int i = 0; i < 4; ++i) {
        float o[8];
#pragma unroll
        for (int j = 0; j < 8; ++j) {
            const float v = acc[i][j] + bb[j];
            o[j] = v > 0.f ? v : 0.f;
        }
        float* op = out + (size_t)(row0 + m0 + i) * H + n0;
        st4(op,     make_float4(o[0], o[1], o[2], o[3]));
        st4(op + 4, make_float4(o[4], o[5], o[6], o[7]));
    }
}

// ---------------------------------------------------------------------------
// Head: out[row] = relu(in[row,:] @ W1 + b1) . w2 + b2[0]   (fp32 for logits)
// ---------------------------------------------------------------------------
__global__ __launch_bounds__(256, 2)
void head_mlp(const float* __restrict__ in, const float* __restrict__ W1,
              const float* __restrict__ b1, const float* __restrict__ w2,
              const float* __restrict__ b2, float* __restrict__ outp)
{
    __shared__ float sA[BM * LDA];
    __shared__ float sW[BK * BN];

    const int tid = threadIdx.x;
    const int rg = tid >> 4, cg = tid & 15;
    const int m0 = rg * 4, n0 = cg * 8;
    const int row0 = blockIdx.x * BM;
    const int lr = tid >> 2, lc = (tid & 3) * 8;
    const int wr = tid >> 3, wc = (tid & 7) * 16;

    float acc[4][8];
#pragma unroll
    for (int i = 0; i < 4; ++i)
#pragma unroll
        for (int j = 0; j < 8; ++j) acc[i][j] = 0.f;

#pragma unroll 1
    for (int kc = 0; kc < 4; ++kc) {
        const int koff = kc * 32;
        const float* srcp = in + (size_t)(row0 + lr) * H + koff + lc;
        st4(&sA[lr * LDA + lc],     ld4(srcp));
        st4(&sA[lr * LDA + lc + 4], ld4(srcp + 4));
        const float* wsrc = W1 + (size_t)koff * BN + wr * BN + wc;
        st4(&sW[wr * BN + wc],      ld4(wsrc));
        st4(&sW[wr * BN + wc + 4],  ld4(wsrc + 4));
        st4(&sW[wr * BN + wc + 8],  ld4(wsrc + 8));
        st4(&sW[wr * BN + wc + 12], ld4(wsrc + 12));
        __syncthreads();
#pragma unroll
        for (int kk = 0; kk < BK; ++kk) {
            float a[4];
#pragma unroll
            for (int i = 0; i < 4; ++i) a[i] = sA[(m0 + i) * LDA + kk];
            const float4 wA = ld4(&sW[kk * BN + n0]);
            const float4 wB = ld4(&sW[kk * BN + n0 + 4]);
            const float w[8] = {wA.x, wA.y, wA.z, wA.w, wB.x, wB.y, wB.z, wB.w};
#pragma unroll
            for (int i = 0; i < 4; ++i)
#pragma unroll
                for (int j = 0; j < 8; ++j)
                    acc[i][j] = fmaf(a[i], w[j], acc[i][j]);
        }
        __syncthreads();
    }

    const float4 bA = ld4(&b1[n0]),  bB = ld4(&b1[n0 + 4]);
    const float4 vA = ld4(&w2[n0]),  vB = ld4(&w2[n0 + 4]);
    const float bb[8] = {bA.x, bA.y, bA.z, bA.w, bB.x, bB.y, bB.z, bB.w};
    const float vv[8] = {vA.x, vA.y, vA.z, vA.w, vB.x, vB.y, vB.z, vB.w};
#pragma unroll
    for (int i = 0; i < 4; ++i) {
        float p = 0.f;
#pragma unroll
        for (int j = 0; j < 8; ++j) {
            float h = acc[i][j] + bb[j];
            h = h > 0.f ? h : 0.f;
            p = fmaf(h, vv[j], p);
        }
        p += __shfl_xor(p, 1, 16); p += __shfl_xor(p, 2, 16);
        p += __shfl_xor(p, 4, 16); p += __shfl_xor(p, 8, 16);
        if (cg == 0) outp[row0 + m0 + i] = p + b2[0];
    }
}

// ---------------------------------------------------------------------------
// CSR build (once per launch; edge_index is fixed)
// ---------------------------------------------------------------------------
__global__ void count_int_k(const int* __restrict__ dst, int* __restrict__ cnt)
{
    const int i = blockIdx.x * 256 + threadIdx.x;
    atomicAdd(&cnt[dst[i]], 1);
}

__global__ void scan_graph_k(const int* __restrict__ cnt, int* __restrict__ off)
{
    __shared__ int s[256];
    const int g = blockIdx.x;
    const int t = threadIdx.x;
    const int a = cnt[g * Pn + 2 * t];
    const int b = cnt[g * Pn + 2 * t + 1];
    s[t] = a + b;
    __syncthreads();
    for (int d = 1; d < 256; d <<= 1) {
        const int v = (t >= d) ? s[t - d] : 0;
        __syncthreads();
        s[t] += v;
        __syncthreads();
    }
    const int excl = s[t] - (a + b);
    off[g * Pn + 2 * t]     = g * EPGn + excl;
    off[g * Pn + 2 * t + 1] = g * EPGn + excl + a;
}

__global__ void place_k(const int* __restrict__ dst, const int* __restrict__ off,
                        int* __restrict__ cur, int* __restrict__ perm)
{
    const int i = blockIdx.x * 256 + threadIdx.x;
    const int d = dst[i];
    const int p = off[d] + atomicAdd(&cur[d], 1);
    perm[p] = i;
}

__global__ void sort_bucket_k(int* __restrict__ perm, const int* __restrict__ off,
                              const int* __restrict__ cnt)
{
    const int n = blockIdx.x * 256 + threadIdx.x;
    if (n >= Nn) return;
    const int o = off[n], c = cnt[n];
    for (int i = 1; i < c; ++i) {
        const int key = perm[o + i];
        int j = i - 1;
        while (j >= 0 && perm[o + j] > key) { perm[o + j + 1] = perm[o + j]; --j; }
        perm[o + j + 1] = key;
    }
}

// agg[n] = mean of incoming edge messages; 32 lanes per node, 4 cols/lane
__global__ __launch_bounds__(256)
void gather_agg_k(const float* __restrict__ he, const int* __restrict__ perm,
                  const int* __restrict__ off, const int* __restrict__ cnt,
                  float* __restrict__ agg)
{
    const int tid = threadIdx.x;
    const int n = blockIdx.x * 8 + (tid >> 5);
    const int c0 = (tid & 31) * 4;
    const int o = off[n], c = cnt[n];
    float ax = 0.f, ay = 0.f, az = 0.f, aw = 0.f;
    for (int k = 0; k < c; ++k) {
        const int eid = perm[o + k];
        const float4 v = ld4(&he[(size_t)eid * H + c0]);
        ax += v.x; ay += v.y; az += v.z; aw += v.w;
    }
    const float inv = 1.f / fmaxf((float)c, 1.f);
    st4(&agg[(size_t)n * H + c0], make_float4(ax * inv, ay * inv, az * inv, aw * inv));
}

// ---------------------------------------------------------------------------
// small utility kernels
// ---------------------------------------------------------------------------
__global__ void init_u_k(float* __restrict__ u, const float* __restrict__ u0)
{
    const int idx = blockIdx.x * 256 + threadIdx.x;
    u[idx] = u0[idx & (H - 1)];
}

__global__ void make_ebatch_k(const int* __restrict__ src, const int* __restrict__ batch,
                              int* __restrict__ eb)
{
    const int i = blockIdx.x * 256 + threadIdx.x;
    eb[i] = batch[src[i]];
}

__global__ void softmax_head_k(const float* __restrict__ logits, float* __restrict__ outp)
{
    const int g = blockIdx.x;
    const int tid = threadIdx.x;
    const float* lg = logits + (size_t)g * Pn;
    const float v0 = lg[tid], v1 = lg[tid + 256];
    float bv; int bi;
    if (v1 > v0) { bv = v1; bi = tid + 256; } else { bv = v0; bi = tid; }

    __shared__ float sv[256];
    __shared__ int   si[256];
    sv[tid] = bv; si[tid] = bi;
    __syncthreads();
    for (int s = 128; s > 0; s >>= 1) {
        if (tid < s) {
            const float ov = sv[tid + s]; const int oi = si[tid + s];
            if (ov > sv[tid] || (ov == sv[tid] && oi < si[tid])) { sv[tid] = ov; si[tid] = oi; }
        }
        __syncthreads();
    }
    const float mx = sv[0];
    const int ai = si[0];
    __syncthreads();

    const float d0 = v0 - mx, d1 = v1 - mx;
    const float e0 = __expf(d0), e1 = __expf(d1);
    __shared__ float ss[256];
    __shared__ float st[256];
    ss[tid] = e0 + e1;
    st[tid] = e0 * d0 + e1 * d1;
    __syncthreads();
    for (int s = 128; s > 0; s >>= 1) {
        if (tid < s) { ss[tid] += ss[tid + s]; st[tid] += st[tid + s]; }
        __syncthreads();
    }
    if (tid == 0) {
        const float S = ss[0];
        const float logS = logf(S);
        outp[g]            = (float)ai;
        outp[Gn + g]       = -logS;
        outp[2 * Gn + g]   = logS - st[0] / S;
    }
}

} // namespace

extern "C" void kernel_launch(void* const* d_in, const int* in_sizes, int n_in,
                              void* d_out, int out_size, void* d_ws, size_t ws_size,
                              hipStream_t stream)
{
    (void)in_sizes; (void)n_in; (void)out_size; (void)ws_size;

    const float* x     = (const float*)d_in[0];
    const float* ea    = (const float*)d_in[1];
    const int*   ei    = (const int*)d_in[2];
    const int*   batch = (const int*)d_in[3];
    const float* Wn  = (const float*)d_in[6];
    const float* bn_ = (const float*)d_in[7];
    const float* We  = (const float*)d_in[8];
    const float* be_ = (const float*)d_in[9];
    const float* u0  = (const float*)d_in[10];
    const float* eW1 = (const float*)d_in[11];
    const float* eb1 = (const float*)d_in[12];
    const float* eW2 = (const float*)d_in[13];
    const float* eb2 = (const float*)d_in[14];
    const float* eg  = (const float*)d_in[15];
    const float* ebn = (const float*)d_in[16];
    const float* nW1 = (const float*)d_in[17];
    const float* nb1 = (const float*)d_in[18];
    const float* nW2 = (const float*)d_in[19];
    const float* nb2 = (const float*)d_in[20];
    const float* ng  = (const float*)d_in[21];
    const float* nbn = (const float*)d_in[22];
    const float* gW1 = (const float*)d_in[23];
    const float* gb1 = (const float*)d_in[24];
    const float* gW2 = (const float*)d_in[25];
    const float* gb2 = (const float*)d_in[26];
    const float* gg  = (const float*)d_in[27];
    const float* gbn = (const float*)d_in[28];
    const float* aW1 = (const float*)d_in[29];
    const float* ab1 = (const float*)d_in[30];
    const float* aW2 = (const float*)d_in[31];
    const float* ab2 = (const float*)d_in[32];
    const float* cW1 = (const float*)d_in[33];
    const float* cb1 = (const float*)d_in[34];
    const float* cW2 = (const float*)d_in[35];
    const float* cb2 = (const float*)d_in[36];

    const int* srcI = ei;
    const int* dstI = ei + En;

    float* ws     = (float*)d_ws;
    float* hx     = ws;                              // N*128
    float* he     = hx + (size_t)Nn * H;             // E*128
    float* agg    = he + (size_t)En * H;             // N*128
    float* u      = agg + (size_t)Nn * H;            // 64*128
    float* nmean  = u + Gn * H;
    float* emean  = nmean + Gn * H;
    float* logits = emean + Gn * H;                  // N
    int*   ebatch = (int*)(logits + Nn);             // E
    int*   cnt    = ebatch + En;                     // N
    int*   off    = cnt + Nn;                        // N
    int*   cur    = off + Nn;                        // N
    int*   perm   = cur + Nn;                        // E
    bf16_t* frag  = (bf16_t*)(perm + En);
    bf16_t* eW1h = frag;              bf16_t* eW1l = eW1h + 512 * 128;   frag += 2 * 512 * 128;
    bf16_t* eW2h = frag;              bf16_t* eW2l = eW2h + 128 * 128;   frag += 2 * 128 * 128;
    bf16_t* nW1h = frag;              bf16_t* nW1l = nW1h + 384 * 128;   frag += 2 * 384 * 128;
    bf16_t* nW2h = frag;              bf16_t* nW2l = nW2h + 128 * 128;   frag += 2 * 128 * 128;
    bf16_t* gW1h = frag;              bf16_t* gW1l = gW1h + 384 * 128;   frag += 2 * 384 * 128;
    bf16_t* gW2h = frag;              bf16_t* gW2l = gW2h + 128 * 128;

    float* outp = (float*)d_out;

    // weight prep
    prep_wfrag<<<(512 * 128) / 256, 256, 0, stream>>>(eW1, eW1h, eW1l);
    prep_wfrag<<<(128 * 128) / 256, 256, 0, stream>>>(eW2, eW2h, eW2l);
    prep_wfrag<<<(384 * 128) / 256, 256, 0, stream>>>(nW1, nW1h, nW1l);
    prep_wfrag<<<(128 * 128) / 256, 256, 0, stream>>>(nW2, nW2h, nW2l);
    prep_wfrag<<<(384 * 128) / 256, 256, 0, stream>>>(gW1, gW1h, gW1l);
    prep_wfrag<<<(128 * 128) / 256, 256, 0, stream>>>(gW2, gW2h, gW2l);

    // CSR build (dst is constant across layers)
    hipMemsetAsync(cnt, 0, Nn * sizeof(int), stream);
    hipMemsetAsync(cur, 0, Nn * sizeof(int), stream);
    count_int_k<<<En / 256, 256, 0, stream>>>(dstI, cnt);
    scan_graph_k<<<Gn, 256, 0, stream>>>(cnt, off);
    place_k<<<En / 256, 256, 0, stream>>>(dstI, off, cur, perm);
    sort_bucket_k<<<(Nn + 255) / 256, 256, 0, stream>>>(perm, off, cnt);

    // input projections + constants
    proj_relu<64><<<Nn / BM, 256, 0, stream>>>(x, Wn, bn_, hx);
    proj_relu<32><<<En / BM, 256, 0, stream>>>(ea, We, be_, he);
    init_u_k<<<(Gn * H) / 256, 256, 0, stream>>>(u, u0);
    make_ebatch_k<<<En / 256, 256, 0, stream>>>(srcI, batch, ebatch);

    for (int l = 0; l < 2; ++l) {
        // edge update (in-place on he) + fused emean pool
        hipMemsetAsync(emean, 0, Gn * H * sizeof(float), stream);
        mfma_mlp_ln<4><<<En / 64, 256, 0, stream>>>(
            hx, srcI, hx, dstI, he, nullptr, u, ebatch,
            eW1h, eW1l, eW2h, eW2l, eb1, eb2, eg, ebn, he,
            emean, 12, 1.f / EPGn);
        // agg = mean of incoming edge messages (CSR gather, deterministic)
        gather_agg_k<<<Nn / 8, 256, 0, stream>>>(he, perm, off, cnt, agg);
        // node update (in-place on hx) + fused nmean pool
        hipMemsetAsync(nmean, 0, Gn * H * sizeof(float), stream);
        mfma_mlp_ln<3><<<Nn / 64, 256, 0, stream>>>(
            hx, nullptr, agg, nullptr, u, batch, nullptr, nullptr,
            nW1h, nW1l, nW2h, nW2l, nb1, nb2, ng, nbn, hx,
            nmean, 9, 1.f / Pn);
        // global update (in-place on u)
        mfma_mlp_ln<3><<<1, 256, 0, stream>>>(
            u, nullptr, nmean, nullptr, emean, nullptr, nullptr, nullptr,
            gW1h, gW1l, gW2h, gW2l, gb1, gb2, gg, gbn, u,
            nullptr, 0, 0.f);
    }

    head_mlp<<<Nn / BM, 256, 0, stream>>>(hx, aW1, ab1, aW2, ab2, logits);
    softmax_head_k<<<Gn, 256, 0, stream>>>(logits, outp);
    head_mlp<<<1, 256, 0, stream>>>(u, cW1, cb1, cW2, cb2, outp + 3 * Gn);
}